// Round 13
// baseline (369.312 us; speedup 1.0000x reference)
//
#include <hip/hip_runtime.h>
#include <hip/hip_bf16.h>
#include <math.h>

#define BB 8
#define LQ 900
#define EE 256
#define NH 8
#define HD 32
#define NL 4
#define NP 4
#define FFN_H 1024

typedef __bf16 bf16x8 __attribute__((ext_vector_type(8)));
typedef float f32x4 __attribute__((ext_vector_type(4)));
typedef unsigned short u16x8 __attribute__((ext_vector_type(8)));

__device__ __forceinline__ unsigned short f2b(float f) {
    union { float f; unsigned int u; } v; v.f = f;
    unsigned int u = v.u;
    unsigned int r = (u + 0x7fffu + ((u >> 16) & 1u)) >> 16;
    return (unsigned short)r;
}
__device__ __forceinline__ float b2f(unsigned short h) {
    union { unsigned int u; float f; } v; v.u = ((unsigned int)h) << 16; return v.f;
}

typedef __attribute__((address_space(3))) unsigned int* lds_ptr_t;
typedef const __attribute__((address_space(1))) unsigned int* gbl_ptr_t;
#define GLOAD16(g, l) __builtin_amdgcn_global_load_lds((gbl_ptr_t)(g), (lds_ptr_t)(l), 16, 0, 0)
#define VMCNT(n) asm volatile("s_waitcnt vmcnt(" #n ")" ::: "memory")
#define LGKM0()  asm volatile("s_waitcnt lgkmcnt(0)" ::: "memory")

// ---------------------------------------------------------------------------
// prep block map (identical to r12, passed):
//   [0,1248) weight transpose | [1248,1252) bias concat | [1252,1284) WopRow
//   [1284,1286) bgg | [1286,8486) ln1 | [8486,10534) memory cast
// ---------------------------------------------------------------------------
struct TDesc { const float* src; unsigned short* dst; int K, N, tile0; };
struct TPack {
    TDesc d[12];
    const float *bq, *bk, *boff, *batt;
    float *bqk, *boa;
    const float *Wop_src, *Wg_src, *bop_src, *bg_src;
    unsigned short* WopRow;
    float* bgg;
};

__global__ __launch_bounds__(256) void prep_kernel(
    TPack p,
    const float* __restrict__ queries, const float* __restrict__ qpos,
    const float* __restrict__ ln1_s, const float* __restrict__ ln1_b,
    unsigned short* __restrict__ x_b, unsigned short* __restrict__ qk_b,
    const float* __restrict__ mem, unsigned short* __restrict__ mem_b, long memN)
{
    const int bi = blockIdx.x;
    const int t = threadIdx.x;

    if (bi < 1248) {
        int di = 0;
#pragma unroll
        for (int i = 1; i < 12; ++i) if (bi >= p.d[i].tile0) di = i;
        TDesc d = p.d[di];
        int tt = bi - d.tile0;
        int tn = (d.N + 31) >> 5;
        int tk = tt / tn, tc = tt % tn;
        __shared__ float tile[32][33];
        int tx = t & 31, ty = t >> 5;
#pragma unroll
        for (int i = 0; i < 4; ++i) {
            int kk = tk * 32 + ty + i * 8, nn = tc * 32 + tx;
            tile[ty + i * 8][tx] = d.src[(size_t)kk * d.N + nn];
        }
        __syncthreads();
#pragma unroll
        for (int i = 0; i < 4; ++i) {
            int nn = tc * 32 + ty + i * 8, kk = tk * 32 + tx;
            d.dst[(size_t)nn * d.K + kk] = f2b(tile[tx][ty + i * 8]);
        }
        return;
    }
    if (bi < 1252) {
        int which = bi - 1248;
        if (which == 0)      p.bqk[t] = p.bq[t];
        else if (which == 1) p.bqk[256 + t] = p.bk[t];
        else if (which == 2) p.boa[t] = p.boff[t];
        else if (t < 128)    p.boa[256 + t] = p.batt[t];
        return;
    }
    if (bi < 1284) {
        long i = ((long)(bi - 1252) * 256 + t) * 8;
        float4 a = *(const float4*)(p.Wop_src + i);
        float4 b = *(const float4*)(p.Wop_src + i + 4);
        u16x8 o;
        o[0] = f2b(a.x); o[1] = f2b(a.y); o[2] = f2b(a.z); o[3] = f2b(a.w);
        o[4] = f2b(b.x); o[5] = f2b(b.y); o[6] = f2b(b.z); o[7] = f2b(b.w);
        *(u16x8*)(p.WopRow + i) = o;
        return;
    }
    if (bi < 1286) {
        int n = (bi - 1284) * 256 + t;
        float bb = p.bg_src[n];
        for (int j = 0; j < 256; ++j)
            bb += p.bop_src[j] * p.Wg_src[(size_t)(256 + j) * 512 + n];
        p.bgg[n] = bb;
        return;
    }
    if (bi < 8486) {
        const int row = bi - 1286;
        const int w = t >> 6, lane = t & 63;
        __shared__ float red[4];
        float v = queries[(size_t)row * EE + t];
        float sum = v;
#pragma unroll
        for (int o = 32; o; o >>= 1) sum += __shfl_xor(sum, o, 64);
        if (lane == 0) red[w] = sum;
        __syncthreads();
        float mean = (red[0] + red[1] + red[2] + red[3]) * (1.0f / 256.0f);
        __syncthreads();
        float dd = v - mean;
        float sq = dd * dd;
#pragma unroll
        for (int o = 32; o; o >>= 1) sq += __shfl_xor(sq, o, 64);
        if (lane == 0) red[w] = sq;
        __syncthreads();
        float var = (red[0] + red[1] + red[2] + red[3]) * (1.0f / 256.0f);
        float y = dd * rsqrtf(var + 1e-5f) * ln1_s[t] + ln1_b[t];
        x_b[(size_t)row * EE + t]  = f2b(y);
        qk_b[(size_t)row * EE + t] = f2b(y + qpos[(size_t)row * EE + t]);
        return;
    }
    {
        long i = ((long)(bi - 8486) * 256 + t) * 8;
        long stride = (long)2048 * 256 * 8;
        for (; i < memN; i += stride) {
            float4 a = *(const float4*)(mem + i);
            float4 b = *(const float4*)(mem + i + 4);
            u16x8 o;
            o[0] = f2b(a.x); o[1] = f2b(a.y); o[2] = f2b(a.z); o[3] = f2b(a.w);
            o[4] = f2b(b.x); o[5] = f2b(b.y); o[6] = f2b(b.z); o[7] = f2b(b.w);
            *(u16x8*)(mem_b + i) = o;
        }
    }
}

// ---------------------------------------------------------------------------
// Batched persistent pipelined bf16 MFMA GEMM, templated on BM,BN.
// 4 waves (2x2); wave tile (BM/2)x(BN/2). Stage = BM/64 + BN/64 gloads/wave.
// BN=256,BM=64 supports fused row-LN epilogue; aF32 path BM=64 only.
// ---------------------------------------------------------------------------
struct GD {
    const unsigned short* A;
    const float* Af;
    const unsigned short* Bt;
    const float* bias;
    const float* resid;
    float* outF;
    unsigned short* outB;
    const float* lnS; const float* lnB; const float* lnAdd;
    unsigned short* lnOut;
    int M, K, N, ntN, tile0, ldOutB, outBoff, act, aF32, ldA;
};
struct GB { GD d[4]; int nd, tot; };

template<int BM, int BN>
__global__ __launch_bounds__(256, (BM + BN <= 256) ? 4 : ((BM == 128) ? 4 : 2))
void gemm_pipe(GB g) {
    __shared__ __align__(16) unsigned short ldsb[2][(BM + BN) * 32];
    __shared__ float lnred[2][64][2];
    const int tid = threadIdx.x;
    const int l = tid & 63, w = tid >> 6;
    const int wr = w >> 1, wc = w & 1;
    constexpr int NI = BM / 32;
    constexpr int NJ = BN / 32;

    int t = blockIdx.x;
    if (t >= g.tot) return;
    int d = 0;
    while (d + 1 < g.nd && t >= g.d[d + 1].tile0) ++d;

    const int sc = tid & 3;
    float4 fA[2];

    auto stage = [&](int dd, int tt, int ks, int pp) {
        const GD& D = g.d[dd];
        const int lda = D.ldA ? D.ldA : D.K;
        int local = tt - D.tile0;
        int m0 = (local / D.ntN) * BM;
        int n0 = (local % D.ntN) * BN;
        unsigned short* base = &ldsb[pp][0];
        if (BM == 64 && D.aF32) {
            int row = tid >> 2;
            int rg = m0 + row; int mm = D.M - 1; rg = rg < mm ? rg : mm;
            int ck = (sc ^ ((row >> 1) & 3)) * 8;
            const float* src = D.Af + (size_t)rg * lda + (ks << 5) + ck;
            fA[0] = *(const float4*)src;
            fA[1] = *(const float4*)(src + 4);
        } else {
#pragma unroll
            for (int ia = 0; ia < BM / 64; ++ia) {
                int row = ia * 64 + w * 16 + (l >> 2);
                int rg = m0 + row; int mm = D.M - 1; rg = rg < mm ? rg : mm;
                int schunk = ((l & 3) ^ ((row >> 1) & 3)) << 4;
                GLOAD16((const char*)(D.A + (size_t)rg * lda + (ks << 5)) + schunk,
                        base + (ia * 64 + w * 16) * 32);
            }
        }
#pragma unroll
        for (int ib = 0; ib < BN / 64; ++ib) {
            int row = ib * 64 + w * 16 + (l >> 2);
            int rg = n0 + row; int nn = D.N - 1; rg = rg < nn ? rg : nn;
            int schunk = ((l & 3) ^ ((row >> 1) & 3)) << 4;
            GLOAD16((const char*)(D.Bt + (size_t)rg * D.K + (ks << 5)) + schunk,
                    base + BM * 32 + (ib * 64 + w * 16) * 32);
        }
    };
    auto commitA = [&](int pp) {
        int row = tid >> 2;
        u16x8 o;
        o[0] = f2b(fA[0].x); o[1] = f2b(fA[0].y); o[2] = f2b(fA[0].z); o[3] = f2b(fA[0].w);
        o[4] = f2b(fA[1].x); o[5] = f2b(fA[1].y); o[6] = f2b(fA[1].z); o[7] = f2b(fA[1].w);
        *(u16x8*)((char*)&ldsb[pp][0] + row * 64 + sc * 16) = o;
    };

    stage(d, t, 0, 0);
    if (BM == 64 && g.d[d].aF32) { commitA(0); LGKM0(); }
    int p = 0;

    while (true) {
        const GD D = g.d[d];
        int local = t - D.tile0;
        const int m0 = (local / D.ntN) * BM;
        const int n0 = (local % D.ntN) * BN;
        const int nk = D.K >> 5;

        f32x4 acc[NI][NJ];
#pragma unroll
        for (int i = 0; i < NI; ++i)
#pragma unroll
            for (int j = 0; j < NJ; ++j) acc[i][j] = (f32x4){0.f, 0.f, 0.f, 0.f};

        for (int ks = 0; ks < nk; ++ks) {
            int nt = t, nks = ks + 1, ndd = d;
            bool have = true;
            if (nks == nk) {
                nt = t + gridDim.x; nks = 0;
                if (nt >= g.tot) have = false;
                else { while (ndd + 1 < g.nd && nt >= g.d[ndd + 1].tile0) ++ndd; }
            }
            bool stagedAF = (BM == 64) && have && g.d[ndd].aF32;
            if (have) {
                stage(ndd, nt, nks, p ^ 1);
                if (stagedAF) {
                    if constexpr (BN == 128) { VMCNT(4); } else { VMCNT(6); }
                } else {
                    if constexpr (BM == 64 && BN == 128) { VMCNT(3); }
                    else if constexpr (BM == 128 && BN == 128) { VMCNT(4); }
                    else { VMCNT(5); }
                }
            } else {
                VMCNT(0);
            }
            __builtin_amdgcn_sched_barrier(0);
            __builtin_amdgcn_s_barrier();
            __builtin_amdgcn_sched_barrier(0);
            {
                const char* base = (const char*)&ldsb[p][0];
                const int rch = ((l >> 4) ^ ((l >> 1) & 3)) << 4;
                bf16x8 af[NI];
#pragma unroll
                for (int i = 0; i < NI; ++i) {
                    int row = wr * (BM / 2) + i * 16 + (l & 15);
                    af[i] = *(const bf16x8*)(base + row * 64 + rch);
                }
#pragma unroll
                for (int j = 0; j < NJ; ++j) {
                    int row = wc * (BN / 2) + j * 16 + (l & 15);
                    bf16x8 bfr = *(const bf16x8*)(base + BM * 64 + row * 64 + rch);
#pragma unroll
                    for (int i = 0; i < NI; ++i)
                        acc[i][j] = __builtin_amdgcn_mfma_f32_16x16x32_bf16(af[i], bfr, acc[i][j], 0, 0, 0);
                }
            }
            if (stagedAF) { commitA(p ^ 1); LGKM0(); }
            __builtin_amdgcn_sched_barrier(0);
            __builtin_amdgcn_s_barrier();
            __builtin_amdgcn_sched_barrier(0);
            p ^= 1;
        }

        // epilogue
#pragma unroll
        for (int i = 0; i < NI; ++i) {
#pragma unroll
            for (int r = 0; r < 4; ++r) {
                int gm = m0 + wr * (BM / 2) + i * 16 + ((l >> 4) << 2) + r;
                if (gm >= D.M) continue;
#pragma unroll
                for (int j = 0; j < NJ; ++j) {
                    int gn = n0 + wc * (BN / 2) + j * 16 + (l & 15);
                    if (gn >= D.N) continue;
                    float v = acc[i][j][r];
                    if (D.bias)  v += D.bias[gn];
                    if (D.resid) v += D.resid[(size_t)gm * D.N + gn];
                    if (D.act == 1)      v = fmaxf(v, 0.f);
                    else if (D.act == 2) v = 1.0f / (1.0f + __expf(-v));
                    acc[i][j][r] = v;
                    if (D.outF) D.outF[(size_t)gm * D.N + gn] = v;
                    if (D.outB) D.outB[(size_t)gm * D.ldOutB + D.outBoff + gn] = f2b(v);
                }
            }
        }

        if constexpr (BM == 64 && BN == 256) {
            if (D.lnOut) {
#pragma unroll
                for (int i = 0; i < NI; ++i) {
#pragma unroll
                    for (int r = 0; r < 4; ++r) {
                        float s1 = 0.f, s2 = 0.f;
#pragma unroll
                        for (int j = 0; j < NJ; ++j) {
                            float v = acc[i][j][r];
                            s1 += v; s2 += v * v;
                        }
#pragma unroll
                        for (int o = 1; o <= 8; o <<= 1) {
                            s1 += __shfl_xor(s1, o, 64);
                            s2 += __shfl_xor(s2, o, 64);
                        }
                        if ((l & 15) == 0) {
                            int row = wr * 32 + i * 16 + ((l >> 4) << 2) + r;
                            lnred[wc][row][0] = s1;
                            lnred[wc][row][1] = s2;
                        }
                    }
                }
                __syncthreads();
#pragma unroll
                for (int i = 0; i < NI; ++i) {
#pragma unroll
                    for (int r = 0; r < 4; ++r) {
                        int row = wr * 32 + i * 16 + ((l >> 4) << 2) + r;
                        int gm = m0 + row;
                        if (gm >= D.M) continue;
                        float mean = (lnred[0][row][0] + lnred[1][row][0]) * (1.0f / 256.0f);
                        float msq  = (lnred[0][row][1] + lnred[1][row][1]) * (1.0f / 256.0f);
                        float rs = rsqrtf(msq - mean * mean + 1e-5f);
#pragma unroll
                        for (int j = 0; j < NJ; ++j) {
                            int gn = wc * 128 + j * 16 + (l & 15);
                            float y = (acc[i][j][r] - mean) * rs * D.lnS[gn] + D.lnB[gn]
                                      + D.lnAdd[(size_t)gm * 256 + gn];
                            D.lnOut[(size_t)gm * 256 + gn] = f2b(y);
                        }
                    }
                }
            }
        }

        t += gridDim.x;
        if (t >= g.tot) break;
        while (d + 1 < g.nd && t >= g.d[d + 1].tile0) ++d;
    }
}

// ---------------------------------------------------------------------------
// Fused MFMA flash self-attention with K/V register prefetch (unchanged).
// ---------------------------------------------------------------------------
__global__ __launch_bounds__(256) void attn_mfma(
    const unsigned short* __restrict__ QK, const unsigned short* __restrict__ Vb,
    unsigned short* __restrict__ outB)
{
    const int qt = blockIdx.x;
    const int bh = blockIdx.y;
    const int b = bh >> 3, h = bh & 7;
    const int tid = threadIdx.x;
    const int w = tid >> 6, l = tid & 63;

    __shared__ __align__(16) unsigned short Ks[64 * 32];
    __shared__ __align__(16) unsigned short VT[32 * 64];
    __shared__ __align__(16) unsigned short Ps[4][64 * 20];

    const int qrow_w = qt * 64 + w * 16;
    int qr = qrow_w + (l & 15); qr = qr < LQ ? qr : LQ - 1;
    bf16x8 qf = *(const bf16x8*)(QK + ((size_t)(b * LQ + qr)) * 512 + h * 32 + (l >> 4) * 8);

    f32x4 acc0 = {0.f, 0.f, 0.f, 0.f}, acc1 = {0.f, 0.f, 0.f, 0.f};
    float m_run = -1e30f, l_run = 0.f;
    const float scale = 0.17677669529663689f;
    const f32x4 z4 = {0.f, 0.f, 0.f, 0.f};

    const int key = tid >> 2;
    const int dg = (tid & 3) * 8;
    u16x8 kvc, vvc, kvn, vvn;
    {
        int krow = key; krow = krow < LQ ? krow : LQ - 1;
        size_t base = (size_t)(b * LQ + krow);
        kvc = *(const u16x8*)(QK + base * 512 + 256 + h * 32 + dg);
        vvc = *(const u16x8*)(Vb + base * 256 + h * 32 + dg);
    }

    for (int kt = 0; kt < 15; ++kt) {
        __syncthreads();
        *(u16x8*)((char*)Ks + key * 64 + ((dg * 2) ^ ((key & 3) << 4))) = kvc;
#pragma unroll
        for (int e = 0; e < 8; ++e) {
            int dd = dg + e;
            *(unsigned short*)((char*)VT + dd * 128 + ((key * 2) ^ ((dd & 7) << 4))) = vvc[e];
        }
        if (kt < 14) {
            int krow = (kt + 1) * 64 + key; krow = krow < LQ ? krow : LQ - 1;
            size_t base = (size_t)(b * LQ + krow);
            kvn = *(const u16x8*)(QK + base * 512 + 256 + h * 32 + dg);
            vvn = *(const u16x8*)(Vb + base * 256 + h * 32 + dg);
        }
        __syncthreads();

        float p[4][4];
        float tmax = -1e30f;
#pragma unroll
        for (int m = 0; m < 4; ++m) {
            int kr = m * 16 + (l & 15);
            bf16x8 kf = *(const bf16x8*)((const char*)Ks + kr * 64 +
                        (((l >> 4) * 16) ^ ((kr & 3) << 4)));
            f32x4 sf = __builtin_amdgcn_mfma_f32_16x16x32_bf16(kf, qf, z4, 0, 0, 0);
#pragma unroll
            for (int r = 0; r < 4; ++r) {
                int kk = kt * 64 + m * 16 + (l >> 4) * 4 + r;
                float sv = (kk < LQ) ? sf[r] * scale : -1e30f;
                p[m][r] = sv;
                tmax = fmaxf(tmax, sv);
            }
        }
        tmax = fmaxf(tmax, __shfl_xor(tmax, 16, 64));
        tmax = fmaxf(tmax, __shfl_xor(tmax, 32, 64));
        float newm = fmaxf(m_run, tmax);
        float corr = __expf(m_run - newm);
        m_run = newm;
        float tsum = 0.f;
#pragma unroll
        for (int m = 0; m < 4; ++m)
#pragma unroll
            for (int r = 0; r < 4; ++r) {
                float e = __expf(p[m][r] - newm);
                p[m][r] = e;
                tsum += e;
            }
        tsum += __shfl_xor(tsum, 16, 64);
        tsum += __shfl_xor(tsum, 32, 64);
        l_run = l_run * corr + tsum;
        acc0 *= corr;
        acc1 *= corr;

        unsigned short* pw = &Ps[w][0];
#pragma unroll
        for (int m = 0; m < 4; ++m)
#pragma unroll
            for (int r = 0; r < 4; ++r) {
                int kk = m * 16 + (l >> 4) * 4 + r;
                pw[kk * 20 + (l & 15)] = f2b(p[m][r]);
            }

#pragma unroll
        for (int s = 0; s < 2; ++s) {
            union { unsigned short u[8]; bf16x8 v; } pb;
#pragma unroll
            for (int j = 0; j < 8; ++j)
                pb.u[j] = pw[(s * 32 + (l >> 4) * 8 + j) * 20 + (l & 15)];
#pragma unroll
            for (int m2 = 0; m2 < 2; ++m2) {
                int dd = m2 * 16 + (l & 15);
                bf16x8 vf = *(const bf16x8*)((const char*)VT + dd * 128 +
                            ((s * 64 + (l >> 4) * 16) ^ ((dd & 7) << 4)));
                if (m2 == 0) acc0 = __builtin_amdgcn_mfma_f32_16x16x32_bf16(vf, pb.v, acc0, 0, 0, 0);
                else         acc1 = __builtin_amdgcn_mfma_f32_16x16x32_bf16(vf, pb.v, acc1, 0, 0, 0);
            }
        }
        if (kt < 14) { kvc = kvn; vvc = vvn; }
    }

    float inv = 1.0f / l_run;
    int q = qrow_w + (l & 15);
    if (q < LQ) {
        size_t obase = ((size_t)(b * LQ + q)) * 256 + h * 32;
#pragma unroll
        for (int r = 0; r < 4; ++r) {
            int d0 = (l >> 4) * 4 + r;
            outB[obase + d0]      = f2b(acc0[r] * inv);
            outB[obase + 16 + d0] = f2b(acc1[r] * inv);
        }
    }
}

// ---------------------------------------------------------------------------
// Fused: sampling-weight softmax + locations + bilinear sampling (unchanged).
// ---------------------------------------------------------------------------
__global__ __launch_bounds__(256) void sample_fused(
    const float* __restrict__ off_att, const float* __restrict__ refp,
    const unsigned short* __restrict__ val,
    const int* __restrict__ shapes, const int* __restrict__ starts,
    float* __restrict__ aw_out, float* __restrict__ loc_out,
    unsigned short* __restrict__ xs, int NV)
{
    const int row = blockIdx.x;
    const int b = row / LQ;
    const int t = threadIdx.x;
    const int h = t >> 5, d = t & 31;

    __shared__ float l_logit[128];
    __shared__ float l_aw[128];
    __shared__ float l_loc[256];
    __shared__ int l_sh[NL * 2];
    __shared__ int l_st[NL];

    if (t < 128) l_logit[t] = off_att[(size_t)row * 384 + 256 + t];
    {
        float o = off_att[(size_t)row * 384 + t];
        int c = t & 1;
        int lv = (t >> 3) & 3;
        float rc = refp[((size_t)row * 4 + lv) * 4 + c];
        float rs = refp[((size_t)row * 4 + lv) * 4 + 2 + c];
        float loc = rc + o * 0.125f * rs;
        l_loc[t] = loc;
        loc_out[(size_t)row * 256 + t] = loc;
    }
    if (t < NL * 2) l_sh[t] = shapes[t];
    if (t < NL) l_st[t] = starts[t];
    __syncthreads();
    if (t < 128) {
        int hh = t >> 4;
        float mx = -1e30f;
#pragma unroll
        for (int i = 0; i < 16; ++i) mx = fmaxf(mx, l_logit[hh * 16 + i]);
        float sum = 0.f;
#pragma unroll
        for (int i = 0; i < 16; ++i) sum += __expf(l_logit[hh * 16 + i] - mx);
        float aw = __expf(l_logit[t] - mx) / sum;
        l_aw[t] = aw;
        aw_out[(size_t)row * 128 + t] = aw;
    }
    __syncthreads();

    float acc = 0.f;
    const unsigned short* vb = val + (size_t)b * NV * EE + h * HD + d;

#pragma unroll
    for (int lv = 0; lv < NL; ++lv) {
        const int Hh = l_sh[lv * 2], Ww = l_sh[lv * 2 + 1];
        const int s0 = l_st[lv];
#pragma unroll
        for (int p = 0; p < NP; ++p) {
            const int base = ((h * NL + lv) * NP + p) * 2;
            float lx = l_loc[base], ly = l_loc[base + 1];
            float wgt0 = l_aw[h * 16 + lv * NP + p];
            float px = lx * (float)Ww - 0.5f;
            float py = ly * (float)Hh - 0.5f;
            float x0f = floorf(px), y0f = floorf(py);
            float wx = px - x0f, wy = py - y0f;
            int x0 = (int)x0f, y0 = (int)y0f;
#pragma unroll
            for (int dy = 0; dy < 2; ++dy) {
                int yi = y0 + dy;
                bool vy = (yi >= 0) && (yi < Hh);
                int yc = min(max(yi, 0), Hh - 1);
                float wyv = dy ? wy : 1.f - wy;
#pragma unroll
                for (int dx = 0; dx < 2; ++dx) {
                    int xi = x0 + dx;
                    bool vv = vy && (xi >= 0) && (xi < Ww);
                    int xc = min(max(xi, 0), Ww - 1);
                    float wgt = wgt0 * wyv * (dx ? wx : 1.f - wx);
                    float gv = b2f(vb[(size_t)(s0 + yc * Ww + xc) * EE]);
                    acc += vv ? wgt * gv : 0.f;
                }
            }
        }
    }
    xs[(size_t)row * 512 + 256 + t] = f2b(acc);
}

// ---------------------------------------------------------------------------
// Gated fusion + ln3 (unchanged).
// ---------------------------------------------------------------------------
__global__ __launch_bounds__(256) void gate_ln3(
    const float* __restrict__ g, const float* __restrict__ x1,
    const float* __restrict__ cross, const float* __restrict__ s,
    const float* __restrict__ bln, float* __restrict__ x2out,
    unsigned short* __restrict__ zb)
{
    const int row = blockIdx.x;
    const int t = threadIdx.x;
    const int w = t >> 6;
    const int lane = t & 63;
    __shared__ float red[4];

    float g1 = g[(size_t)row * 512 + t];
    float g2 = g[(size_t)row * 512 + 256 + t];
    float v = g1 * x1[(size_t)row * EE + t] + g2 * cross[(size_t)row * EE + t];
    x2out[(size_t)row * EE + t] = v;

    float sum = v;
#pragma unroll
    for (int o = 32; o; o >>= 1) sum += __shfl_xor(sum, o, 64);
    if (lane == 0) red[w] = sum;
    __syncthreads();
    float mean = (red[0] + red[1] + red[2] + red[3]) * (1.0f / 256.0f);
    __syncthreads();

    float d = v - mean;
    float sq = d * d;
#pragma unroll
    for (int o = 32; o; o >>= 1) sq += __shfl_xor(sq, o, 64);
    if (lane == 0) red[w] = sq;
    __syncthreads();
    float var = (red[0] + red[1] + red[2] + red[3]) * (1.0f / 256.0f);

    float y = d * rsqrtf(var + 1e-5f) * s[t] + bln[t];
    zb[(size_t)row * EE + t] = f2b(y);
}

// ---------------------------------------------------------------------------
extern "C" void kernel_launch(void* const* d_in, const int* in_sizes, int n_in,
                              void* d_out, int out_size, void* d_ws, size_t ws_size,
                              hipStream_t stream)
{
    const float* queries   = (const float*)d_in[0];
    const float* memory    = (const float*)d_in[1];
    const float* query_pos = (const float*)d_in[2];
    const float* refp      = (const float*)d_in[3];
    const int*   shapes    = (const int*)d_in[4];
    const int*   starts    = (const int*)d_in[5];
    const float* Wq  = (const float*)d_in[6],  *bq  = (const float*)d_in[7];
    const float* Wk  = (const float*)d_in[8],  *bk  = (const float*)d_in[9];
    const float* Wv  = (const float*)d_in[10], *bv  = (const float*)d_in[11];
    const float* Wo  = (const float*)d_in[12], *bo  = (const float*)d_in[13];
    const float* Wvd = (const float*)d_in[14], *bvd = (const float*)d_in[15];
    const float* Woff= (const float*)d_in[16], *boff= (const float*)d_in[17];
    const float* Watt= (const float*)d_in[18], *batt= (const float*)d_in[19];
    const float* Wop = (const float*)d_in[20], *bop = (const float*)d_in[21];
    const float* Wg  = (const float*)d_in[22], *bg  = (const float*)d_in[23];
    const float* W1  = (const float*)d_in[24], *b1  = (const float*)d_in[25];
    const float* W2  = (const float*)d_in[26], *b2  = (const float*)d_in[27];
    const float* ln1_s = (const float*)d_in[28], *ln1_b = (const float*)d_in[29];
    const float* ln2_s = (const float*)d_in[30], *ln2_b = (const float*)d_in[31];
    const float* ln3_s = (const float*)d_in[32], *ln3_b = (const float*)d_in[33];

    const int NV = in_sizes[1] / (BB * EE);   // 13294
    const int Mq = BB * LQ;                   // 7200
    const int Mv = BB * NV;                   // 106352
    const long memN = (long)Mv * EE;

    char* W8 = (char*)d_ws;
    size_t off = 0;
    auto alloc = [&](size_t bytes) { char* p = W8 + off; off += (bytes + 255) & ~(size_t)255; return p; };

    unsigned short* mem_b = (unsigned short*)alloc((size_t)memN * 2);
    unsigned short* val_b = (unsigned short*)alloc((size_t)memN * 2);
    unsigned short* WtQK  = (unsigned short*)alloc(512 * 256 * 2);
    unsigned short* WtV   = (unsigned short*)alloc(256 * 256 * 2);
    unsigned short* WtO   = (unsigned short*)alloc(256 * 256 * 2);
    unsigned short* WtVD  = (unsigned short*)alloc(256 * 256 * 2);
    unsigned short* WtOA  = (unsigned short*)alloc(384 * 256 * 2);
    unsigned short* WtOP  = (unsigned short*)alloc(256 * 256 * 2);
    unsigned short* WtGF  = (unsigned short*)alloc(512 * 512 * 2);
    unsigned short* Wg2T  = (unsigned short*)alloc(512 * 256 * 2);
    unsigned short* WopRow= (unsigned short*)alloc(256 * 256 * 2);
    unsigned short* Wt1   = (unsigned short*)alloc(1024 * 256 * 2);
    unsigned short* Wt2   = (unsigned short*)alloc(256 * 1024 * 2);
    float*          bqk   = (float*)alloc(512 * 4);
    float*          boa   = (float*)alloc(384 * 4);
    float*          bgg   = (float*)alloc(512 * 4);
    unsigned short* qkb   = (unsigned short*)alloc((size_t)Mq * 512 * 2);
    unsigned short* vb_buf= (unsigned short*)alloc((size_t)Mq * 256 * 2);
    unsigned short* av_buf= (unsigned short*)alloc((size_t)Mq * 256 * 2);
    float*          x1    = (float*)alloc((size_t)Mq * 256 * 4);
    unsigned short* xs_cat= (unsigned short*)alloc((size_t)Mq * 512 * 2);
    unsigned short* qc_b  = (unsigned short*)alloc((size_t)Mq * 256 * 2);
    unsigned short* qk_b  = (unsigned short*)alloc((size_t)Mq * 256 * 2);
    float*          cross = (float*)alloc((size_t)Mq * 256 * 4);

    unsigned short* x_b = (unsigned short*)cross;
    float* off_att = (float*)qkb;
    float* gbuf = (float*)mem_b;
    float* x2   = (float*)((char*)mem_b + (size_t)Mq * 512 * 4);
    unsigned short* z_b = (unsigned short*)((char*)x2 + (size_t)Mq * 256 * 4);
    unsigned short* hidden_b = (unsigned short*)((char*)z_b + (size_t)Mq * 256 * 2);

    float* out0    = (float*)d_out;
    float* aw_out  = out0 + (size_t)Mq * 256;
    float* loc_out = aw_out + (size_t)Mq * 128;

    dim3 blk(256);
    const int tMq64  = (Mq + 63) / 64;     // 113
    const int tMq128 = (Mq + 127) / 128;   // 57
    const int tv128  = (Mv + 127) / 128;   // 831

    // 1. prep
    TPack tp;
    tp.d[0]  = { Wq,             WtQK,             256, 256,    0 };
    tp.d[1]  = { Wk,             WtQK + 256 * 256, 256, 256,   64 };
    tp.d[2]  = { Wv,             WtV,              256, 256,  128 };
    tp.d[3]  = { Wo,             WtO,              256, 256,  192 };
    tp.d[4]  = { Wvd,            WtVD,             256, 256,  256 };
    tp.d[5]  = { Woff,           WtOA,             256, 256,  320 };
    tp.d[6]  = { Watt,           WtOA + 256 * 256, 256, 128,  384 };
    tp.d[7]  = { Wop,            WtOP,             256, 256,  416 };
    tp.d[8]  = { Wg,             WtGF,             512, 512,  480 };  // 128 tiles: Wg1^T
    tp.d[9]  = { Wg + 256 * 512, Wg2T,             256, 512,  608 };  // 128 tiles: Wg2^T
    tp.d[10] = { W1,             Wt1,              256, 1024, 736 };
    tp.d[11] = { W2,             Wt2,             1024, 256,  992 };
    tp.bq = bq; tp.bk = bk; tp.boff = boff; tp.batt = batt;
    tp.bqk = bqk; tp.boa = boa;
    tp.Wop_src = Wop; tp.Wg_src = Wg; tp.bop_src = bop; tp.bg_src = bg;
    tp.WopRow = WopRow; tp.bgg = bgg;
    prep_kernel<<<10534, blk, 0, stream>>>(
        tp, queries, query_pos, ln1_s, ln1_b, x_b, qk_b, memory, mem_b, memN);

    // 2. batched {VAL, QK, V, WopG} — persistent BM=128 x BN=128
    {
        GB g; g.nd = 4;
        g.d[0] = { mem_b, nullptr, WtVD, bvd, nullptr, nullptr, val_b,
                   nullptr, nullptr, nullptr, nullptr,
                   Mv, 256, 256, 2, 0, 256, 0, 0, 0, 0 };
        g.d[1] = { qk_b, nullptr, WtQK, bqk, nullptr, nullptr, qkb,
                   nullptr, nullptr, nullptr, nullptr,
                   Mq, 256, 512, 4, tv128 * 2, 512, 0, 0, 0, 0 };
        g.d[2] = { x_b, nullptr, WtV, bv, nullptr, nullptr, vb_buf,
                   nullptr, nullptr, nullptr, nullptr,
                   Mq, 256, 256, 2, tv128 * 2 + tMq128 * 4, 256, 0, 0, 0, 0 };
        g.d[3] = { Wg2T, nullptr, WopRow, nullptr, nullptr, nullptr, WtGF,
                   nullptr, nullptr, nullptr, nullptr,
                   512, 256, 256, 2, tv128 * 2 + tMq128 * 6, 512, 256, 0, 0, 0 };
        g.tot = tv128 * 2 + tMq128 * 6 + 8;   // 2012
        gemm_pipe<128, 128><<<1536, blk, 0, stream>>>(g);
    }

    // 3. self-attention
    attn_mfma<<<dim3(15, BB * NH), blk, 0, stream>>>(qkb, vb_buf, av_buf);

    // 4. x1 = attnV @ Wo + bo + queries; fused ln2(+pos) -> qc_b  (BM=64,BN=256)
    {
        GB g; g.nd = 1;
        g.d[0] = { av_buf, nullptr, WtO, bo, queries, x1, xs_cat,
                   ln2_s, ln2_b, query_pos, qc_b,
                   Mq, 256, 256, 1, 0, 512, 0, 0, 0, 0 };
        g.tot = tMq64;
        gemm_pipe<64, 256><<<tMq64, blk, 0, stream>>>(g);
    }

    // 5. off|att logits
    {
        GB g; g.nd = 1;
        g.d[0] = { qc_b, nullptr, WtOA, boa, nullptr, off_att, nullptr,
                   nullptr, nullptr, nullptr, nullptr,
                   Mq, 256, 384, 3, 0, 384, 0, 0, 0, 0 };
        g.tot = tMq128 * 3;   // 171
        gemm_pipe<128, 128><<<g.tot, blk, 0, stream>>>(g);
    }

    // 6. softmax + loc + bilinear sampling -> xs_cat[:,256:]
    sample_fused<<<Mq, blk, 0, stream>>>(off_att, refp, val_b, shapes, starts,
                                         aw_out, loc_out, xs_cat, NV);

    // 7. batched { cross, g=sigmoid([x1|samp]@WtGF+bgg) }
    {
        GB g; g.nd = 2;
        g.d[0] = { xs_cat + 256, nullptr, WtOP, bop, nullptr, cross, nullptr,
                   nullptr, nullptr, nullptr, nullptr,
                   Mq, 256, 256, 2, 0, 0, 0, 0, 0, 512 };
        g.d[1] = { xs_cat, nullptr, WtGF, bgg, nullptr, gbuf, nullptr,
                   nullptr, nullptr, nullptr, nullptr,
                   Mq, 512, 512, 4, tMq128 * 2, 0, 0, 2, 0, 0 };
        g.tot = tMq128 * 6;   // 342
        gemm_pipe<128, 128><<<g.tot, blk, 0, stream>>>(g);
    }

    // 8. x2 + ln3
    gate_ln3<<<Mq, blk, 0, stream>>>(gbuf, x1, cross, ln3_s, ln3_b, x2, z_b);

    // 9. hidden = relu(z @ W1 + b1)
    {
        GB g; g.nd = 1;
        g.d[0] = { z_b, nullptr, Wt1, b1, nullptr, nullptr, hidden_b,
                   nullptr, nullptr, nullptr, nullptr,
                   Mq, 256, 1024, 8, 0, 1024, 0, 1, 0, 0 };
        g.tot = tMq128 * 8;   // 456
        gemm_pipe<128, 128><<<g.tot, blk, 0, stream>>>(g);
    }

    // 10. out0 = hidden @ W2 + b2 + x2
    {
        GB g; g.nd = 1;
        g.d[0] = { hidden_b, nullptr, Wt2, b2, x2, out0, nullptr,
                   nullptr, nullptr, nullptr, nullptr,
                   Mq, 1024, 256, 2, 0, 256, 0, 0, 0, 0 };
        g.tot = tMq128 * 2;   // 114
        gemm_pipe<128, 128><<<g.tot, blk, 0, stream>>>(g);
    }
}

// Round 14
// 346.433 us; speedup vs baseline: 1.0660x; 1.0660x over previous
//
#include <hip/hip_runtime.h>
#include <hip/hip_bf16.h>
#include <math.h>

#define BB 8
#define LQ 900
#define EE 256
#define NH 8
#define HD 32
#define NL 4
#define NP 4
#define FFN_H 1024

typedef __bf16 bf16x8 __attribute__((ext_vector_type(8)));
typedef float f32x4 __attribute__((ext_vector_type(4)));
typedef unsigned short u16x8 __attribute__((ext_vector_type(8)));

__device__ __forceinline__ unsigned short f2b(float f) {
    union { float f; unsigned int u; } v; v.f = f;
    unsigned int u = v.u;
    unsigned int r = (u + 0x7fffu + ((u >> 16) & 1u)) >> 16;
    return (unsigned short)r;
}
__device__ __forceinline__ float b2f(unsigned short h) {
    union { unsigned int u; float f; } v; v.u = ((unsigned int)h) << 16; return v.f;
}

typedef __attribute__((address_space(3))) unsigned int* lds_ptr_t;
typedef const __attribute__((address_space(1))) unsigned int* gbl_ptr_t;
#define GLOAD16(g, l) __builtin_amdgcn_global_load_lds((gbl_ptr_t)(g), (lds_ptr_t)(l), 16, 0, 0)
#define VMCNT(n) asm volatile("s_waitcnt vmcnt(" #n ")" ::: "memory")

// ---------------------------------------------------------------------------
// prep block map (identical to r12, passed):
//   [0,1248) weight transpose | [1248,1252) bias concat | [1252,1284) WopRow
//   [1284,1286) bgg | [1286,8486) ln1 | [8486,10534) memory cast
// ---------------------------------------------------------------------------
struct TDesc { const float* src; unsigned short* dst; int K, N, tile0; };
struct TPack {
    TDesc d[12];
    const float *bq, *bk, *boff, *batt;
    float *bqk, *boa;
    const float *Wop_src, *Wg_src, *bop_src, *bg_src;
    unsigned short* WopRow;
    float* bgg;
};

__global__ __launch_bounds__(256) void prep_kernel(
    TPack p,
    const float* __restrict__ queries, const float* __restrict__ qpos,
    const float* __restrict__ ln1_s, const float* __restrict__ ln1_b,
    unsigned short* __restrict__ x_b, unsigned short* __restrict__ qk_b,
    const float* __restrict__ mem, unsigned short* __restrict__ mem_b, long memN)
{
    const int bi = blockIdx.x;
    const int t = threadIdx.x;

    if (bi < 1248) {
        int di = 0;
#pragma unroll
        for (int i = 1; i < 12; ++i) if (bi >= p.d[i].tile0) di = i;
        TDesc d = p.d[di];
        int tt = bi - d.tile0;
        int tn = (d.N + 31) >> 5;
        int tk = tt / tn, tc = tt % tn;
        __shared__ float tile[32][33];
        int tx = t & 31, ty = t >> 5;
#pragma unroll
        for (int i = 0; i < 4; ++i) {
            int kk = tk * 32 + ty + i * 8, nn = tc * 32 + tx;
            tile[ty + i * 8][tx] = d.src[(size_t)kk * d.N + nn];
        }
        __syncthreads();
#pragma unroll
        for (int i = 0; i < 4; ++i) {
            int nn = tc * 32 + ty + i * 8, kk = tk * 32 + tx;
            d.dst[(size_t)nn * d.K + kk] = f2b(tile[tx][ty + i * 8]);
        }
        return;
    }
    if (bi < 1252) {
        int which = bi - 1248;
        if (which == 0)      p.bqk[t] = p.bq[t];
        else if (which == 1) p.bqk[256 + t] = p.bk[t];
        else if (which == 2) p.boa[t] = p.boff[t];
        else if (t < 128)    p.boa[256 + t] = p.batt[t];
        return;
    }
    if (bi < 1284) {
        long i = ((long)(bi - 1252) * 256 + t) * 8;
        float4 a = *(const float4*)(p.Wop_src + i);
        float4 b = *(const float4*)(p.Wop_src + i + 4);
        u16x8 o;
        o[0] = f2b(a.x); o[1] = f2b(a.y); o[2] = f2b(a.z); o[3] = f2b(a.w);
        o[4] = f2b(b.x); o[5] = f2b(b.y); o[6] = f2b(b.z); o[7] = f2b(b.w);
        *(u16x8*)(p.WopRow + i) = o;
        return;
    }
    if (bi < 1286) {
        int n = (bi - 1284) * 256 + t;
        float bb = p.bg_src[n];
        for (int j = 0; j < 256; ++j)
            bb += p.bop_src[j] * p.Wg_src[(size_t)(256 + j) * 512 + n];
        p.bgg[n] = bb;
        return;
    }
    if (bi < 8486) {
        const int row = bi - 1286;
        const int w = t >> 6, lane = t & 63;
        __shared__ float red[4];
        float v = queries[(size_t)row * EE + t];
        float sum = v;
#pragma unroll
        for (int o = 32; o; o >>= 1) sum += __shfl_xor(sum, o, 64);
        if (lane == 0) red[w] = sum;
        __syncthreads();
        float mean = (red[0] + red[1] + red[2] + red[3]) * (1.0f / 256.0f);
        __syncthreads();
        float dd = v - mean;
        float sq = dd * dd;
#pragma unroll
        for (int o = 32; o; o >>= 1) sq += __shfl_xor(sq, o, 64);
        if (lane == 0) red[w] = sq;
        __syncthreads();
        float var = (red[0] + red[1] + red[2] + red[3]) * (1.0f / 256.0f);
        float y = dd * rsqrtf(var + 1e-5f) * ln1_s[t] + ln1_b[t];
        x_b[(size_t)row * EE + t]  = f2b(y);
        qk_b[(size_t)row * EE + t] = f2b(y + qpos[(size_t)row * EE + t]);
        return;
    }
    {
        long i = ((long)(bi - 8486) * 256 + t) * 8;
        long stride = (long)2048 * 256 * 8;
        for (; i < memN; i += stride) {
            float4 a = *(const float4*)(mem + i);
            float4 b = *(const float4*)(mem + i + 4);
            u16x8 o;
            o[0] = f2b(a.x); o[1] = f2b(a.y); o[2] = f2b(a.z); o[3] = f2b(a.w);
            o[4] = f2b(b.x); o[5] = f2b(b.y); o[6] = f2b(b.z); o[7] = f2b(b.w);
            *(u16x8*)(mem_b + i) = o;
        }
    }
}

// ---------------------------------------------------------------------------
// Batched persistent pipelined bf16 MFMA GEMM (BM=64, template BN).
// BN=128: 3-buffer LDS ring, 2-deep staging (counted vmcnt 6/3/0, 3 gloads
// per stage). BN=256: 2-buffer (5/0), supports fused row-LN epilogue.
// C = act(A[M,K] @ Bt[N,K]^T + bias + resid); ldA runtime (0 => K).
// ---------------------------------------------------------------------------
struct GD {
    const unsigned short* A;
    const unsigned short* Bt;
    const float* bias;
    const float* resid;
    float* outF;
    unsigned short* outB;
    const float* lnS; const float* lnB; const float* lnAdd;
    unsigned short* lnOut;
    int M, K, N, ntN, tile0, ldOutB, outBoff, act, ldA;
};
struct GB { GD d[4]; int nd, tot; };

template<int BN>
__global__ __launch_bounds__(256, (BN == 128) ? 4 : 2) void gemm_pipe(GB g) {
    constexpr int STAGES = (BN == 128) ? 3 : 2;
    __shared__ __align__(16) unsigned short ldsb[STAGES][(64 + BN) * 32];
    __shared__ float lnred[2][64][2];
    const int tid = threadIdx.x;
    const int l = tid & 63, w = tid >> 6;
    const int wr = w >> 1, wc = w & 1;
    constexpr int NJ = BN / 32;

    int t = blockIdx.x;
    if (t >= g.tot) return;
    int d = 0;
    while (d + 1 < g.nd && t >= g.d[d + 1].tile0) ++d;

    auto stage = [&](int dd, int tt, int ks, int pp) {
        const GD& D = g.d[dd];
        const int lda = D.ldA ? D.ldA : D.K;
        int local = tt - D.tile0;
        int m0 = (local / D.ntN) * 64;
        int n0 = (local % D.ntN) * BN;
        unsigned short* base = &ldsb[pp][0];
        {
            int row = w * 16 + (l >> 2);
            int rg = m0 + row; int mm = D.M - 1; rg = rg < mm ? rg : mm;
            int schunk = ((l & 3) ^ ((row >> 1) & 3)) << 4;
            GLOAD16((const char*)(D.A + (size_t)rg * lda + (ks << 5)) + schunk,
                    base + (w * 16) * 32);
        }
#pragma unroll
        for (int ib = 0; ib < BN / 64; ++ib) {
            int row = ib * 64 + w * 16 + (l >> 2);
            int rg = n0 + row; int nn = D.N - 1; rg = rg < nn ? rg : nn;
            int schunk = ((l & 3) ^ ((row >> 1) & 3)) << 4;
            GLOAD16((const char*)(D.Bt + (size_t)rg * D.K + (ks << 5)) + schunk,
                    base + 2048 + (ib * 64 + w * 16) * 32);
        }
    };

    // staging cursor (runs STAGES-1 steps ahead of compute)
    int st_t = t, st_ks = 0, st_d = d;
    bool st_valid = true;
    auto advance = [&]() {
        ++st_ks;
        if (st_ks == (g.d[st_d].K >> 5)) {
            st_ks = 0;
            st_t += gridDim.x;
            if (st_t >= g.tot) { st_valid = false; }
            else { while (st_d + 1 < g.nd && st_t >= g.d[st_d + 1].tile0) ++st_d; }
        }
    };

    int sp = 0, cp = 0, nf = 0;
    stage(st_d, st_t, st_ks, sp); sp = (sp + 1 == STAGES) ? 0 : sp + 1; ++nf; advance();
    if (STAGES == 3 && st_valid) {
        stage(st_d, st_t, st_ks, sp); sp = (sp + 1 == STAGES) ? 0 : sp + 1; ++nf; advance();
    }

    while (true) {
        const GD D = g.d[d];
        int local = t - D.tile0;
        const int m0 = (local / D.ntN) * 64;
        const int n0 = (local % D.ntN) * BN;
        const int nk = D.K >> 5;

        f32x4 acc[2][NJ];
#pragma unroll
        for (int i = 0; i < 2; ++i)
#pragma unroll
            for (int j = 0; j < NJ; ++j) acc[i][j] = (f32x4){0.f, 0.f, 0.f, 0.f};

        for (int ks = 0; ks < nk; ++ks) {
            if (st_valid && nf < STAGES) {
                stage(st_d, st_t, st_ks, sp);
                sp = (sp + 1 == STAGES) ? 0 : sp + 1;
                ++nf; advance();
            }
            if (nf == 3)      { VMCNT(6); }
            else if (nf == 2) { if constexpr (BN == 128) { VMCNT(3); } else { VMCNT(5); } }
            else              { VMCNT(0); }
            __builtin_amdgcn_sched_barrier(0);
            __builtin_amdgcn_s_barrier();
            __builtin_amdgcn_sched_barrier(0);
            {
                const char* base = (const char*)&ldsb[cp][0];
                const int rch = ((l >> 4) ^ ((l >> 1) & 3)) << 4;
                bf16x8 af[2];
#pragma unroll
                for (int i = 0; i < 2; ++i) {
                    int row = wr * 32 + i * 16 + (l & 15);
                    af[i] = *(const bf16x8*)(base + row * 64 + rch);
                }
#pragma unroll
                for (int j = 0; j < NJ; ++j) {
                    int row = wc * (BN / 2) + j * 16 + (l & 15);
                    bf16x8 bfr = *(const bf16x8*)(base + 4096 + row * 64 + rch);
#pragma unroll
                    for (int i = 0; i < 2; ++i)
                        acc[i][j] = __builtin_amdgcn_mfma_f32_16x16x32_bf16(af[i], bfr, acc[i][j], 0, 0, 0);
                }
            }
            __builtin_amdgcn_sched_barrier(0);
            __builtin_amdgcn_s_barrier();
            __builtin_amdgcn_sched_barrier(0);
            cp = (cp + 1 == STAGES) ? 0 : cp + 1;
            --nf;
        }

        // epilogue
#pragma unroll
        for (int i = 0; i < 2; ++i) {
#pragma unroll
            for (int r = 0; r < 4; ++r) {
                int gm = m0 + wr * 32 + i * 16 + ((l >> 4) << 2) + r;
                if (gm >= D.M) continue;
#pragma unroll
                for (int j = 0; j < NJ; ++j) {
                    int gn = n0 + wc * (BN / 2) + j * 16 + (l & 15);
                    if (gn >= D.N) continue;
                    float v = acc[i][j][r];
                    if (D.bias)  v += D.bias[gn];
                    if (D.resid) v += D.resid[(size_t)gm * D.N + gn];
                    if (D.act == 1)      v = fmaxf(v, 0.f);
                    else if (D.act == 2) v = 1.0f / (1.0f + __expf(-v));
                    acc[i][j][r] = v;
                    if (D.outF) D.outF[(size_t)gm * D.N + gn] = v;
                    if (D.outB) D.outB[(size_t)gm * D.ldOutB + D.outBoff + gn] = f2b(v);
                }
            }
        }

        if constexpr (BN == 256) {
            if (D.lnOut) {
#pragma unroll
                for (int i = 0; i < 2; ++i) {
#pragma unroll
                    for (int r = 0; r < 4; ++r) {
                        float s1 = 0.f, s2 = 0.f;
#pragma unroll
                        for (int j = 0; j < NJ; ++j) {
                            float v = acc[i][j][r];
                            s1 += v; s2 += v * v;
                        }
#pragma unroll
                        for (int o = 1; o <= 8; o <<= 1) {
                            s1 += __shfl_xor(s1, o, 64);
                            s2 += __shfl_xor(s2, o, 64);
                        }
                        if ((l & 15) == 0) {
                            int row = wr * 32 + i * 16 + ((l >> 4) << 2) + r;
                            lnred[wc][row][0] = s1;
                            lnred[wc][row][1] = s2;
                        }
                    }
                }
                __syncthreads();
#pragma unroll
                for (int i = 0; i < 2; ++i) {
#pragma unroll
                    for (int r = 0; r < 4; ++r) {
                        int row = wr * 32 + i * 16 + ((l >> 4) << 2) + r;
                        int gm = m0 + row;
                        if (gm >= D.M) continue;
                        float mean = (lnred[0][row][0] + lnred[1][row][0]) * (1.0f / 256.0f);
                        float msq  = (lnred[0][row][1] + lnred[1][row][1]) * (1.0f / 256.0f);
                        float rs = rsqrtf(msq - mean * mean + 1e-5f);
#pragma unroll
                        for (int j = 0; j < NJ; ++j) {
                            int gn = wc * 128 + j * 16 + (l & 15);
                            float y = (acc[i][j][r] - mean) * rs * D.lnS[gn] + D.lnB[gn]
                                      + D.lnAdd[(size_t)gm * 256 + gn];
                            D.lnOut[(size_t)gm * 256 + gn] = f2b(y);
                        }
                    }
                }
            }
        }

        t += gridDim.x;
        if (t >= g.tot) break;
        while (d + 1 < g.nd && t >= g.d[d + 1].tile0) ++d;
    }
}

// ---------------------------------------------------------------------------
// Fused MFMA flash self-attention with K/V register prefetch (unchanged).
// ---------------------------------------------------------------------------
__global__ __launch_bounds__(256) void attn_mfma(
    const unsigned short* __restrict__ QK, const unsigned short* __restrict__ Vb,
    unsigned short* __restrict__ outB)
{
    const int qt = blockIdx.x;
    const int bh = blockIdx.y;
    const int b = bh >> 3, h = bh & 7;
    const int tid = threadIdx.x;
    const int w = tid >> 6, l = tid & 63;

    __shared__ __align__(16) unsigned short Ks[64 * 32];
    __shared__ __align__(16) unsigned short VT[32 * 64];
    __shared__ __align__(16) unsigned short Ps[4][64 * 20];

    const int qrow_w = qt * 64 + w * 16;
    int qr = qrow_w + (l & 15); qr = qr < LQ ? qr : LQ - 1;
    bf16x8 qf = *(const bf16x8*)(QK + ((size_t)(b * LQ + qr)) * 512 + h * 32 + (l >> 4) * 8);

    f32x4 acc0 = {0.f, 0.f, 0.f, 0.f}, acc1 = {0.f, 0.f, 0.f, 0.f};
    float m_run = -1e30f, l_run = 0.f;
    const float scale = 0.17677669529663689f;
    const f32x4 z4 = {0.f, 0.f, 0.f, 0.f};

    const int key = tid >> 2;
    const int dg = (tid & 3) * 8;
    u16x8 kvc, vvc, kvn, vvn;
    {
        int krow = key; krow = krow < LQ ? krow : LQ - 1;
        size_t base = (size_t)(b * LQ + krow);
        kvc = *(const u16x8*)(QK + base * 512 + 256 + h * 32 + dg);
        vvc = *(const u16x8*)(Vb + base * 256 + h * 32 + dg);
    }

    for (int kt = 0; kt < 15; ++kt) {
        __syncthreads();
        *(u16x8*)((char*)Ks + key * 64 + ((dg * 2) ^ ((key & 3) << 4))) = kvc;
#pragma unroll
        for (int e = 0; e < 8; ++e) {
            int dd = dg + e;
            *(unsigned short*)((char*)VT + dd * 128 + ((key * 2) ^ ((dd & 7) << 4))) = vvc[e];
        }
        if (kt < 14) {
            int krow = (kt + 1) * 64 + key; krow = krow < LQ ? krow : LQ - 1;
            size_t base = (size_t)(b * LQ + krow);
            kvn = *(const u16x8*)(QK + base * 512 + 256 + h * 32 + dg);
            vvn = *(const u16x8*)(Vb + base * 256 + h * 32 + dg);
        }
        __syncthreads();

        float p[4][4];
        float tmax = -1e30f;
#pragma unroll
        for (int m = 0; m < 4; ++m) {
            int kr = m * 16 + (l & 15);
            bf16x8 kf = *(const bf16x8*)((const char*)Ks + kr * 64 +
                        (((l >> 4) * 16) ^ ((kr & 3) << 4)));
            f32x4 sf = __builtin_amdgcn_mfma_f32_16x16x32_bf16(kf, qf, z4, 0, 0, 0);
#pragma unroll
            for (int r = 0; r < 4; ++r) {
                int kk = kt * 64 + m * 16 + (l >> 4) * 4 + r;
                float sv = (kk < LQ) ? sf[r] * scale : -1e30f;
                p[m][r] = sv;
                tmax = fmaxf(tmax, sv);
            }
        }
        tmax = fmaxf(tmax, __shfl_xor(tmax, 16, 64));
        tmax = fmaxf(tmax, __shfl_xor(tmax, 32, 64));
        float newm = fmaxf(m_run, tmax);
        float corr = __expf(m_run - newm);
        m_run = newm;
        float tsum = 0.f;
#pragma unroll
        for (int m = 0; m < 4; ++m)
#pragma unroll
            for (int r = 0; r < 4; ++r) {
                float e = __expf(p[m][r] - newm);
                p[m][r] = e;
                tsum += e;
            }
        tsum += __shfl_xor(tsum, 16, 64);
        tsum += __shfl_xor(tsum, 32, 64);
        l_run = l_run * corr + tsum;
        acc0 *= corr;
        acc1 *= corr;

        unsigned short* pw = &Ps[w][0];
#pragma unroll
        for (int m = 0; m < 4; ++m)
#pragma unroll
            for (int r = 0; r < 4; ++r) {
                int kk = m * 16 + (l >> 4) * 4 + r;
                pw[kk * 20 + (l & 15)] = f2b(p[m][r]);
            }

#pragma unroll
        for (int s = 0; s < 2; ++s) {
            union { unsigned short u[8]; bf16x8 v; } pb;
#pragma unroll
            for (int j = 0; j < 8; ++j)
                pb.u[j] = pw[(s * 32 + (l >> 4) * 8 + j) * 20 + (l & 15)];
#pragma unroll
            for (int m2 = 0; m2 < 2; ++m2) {
                int dd = m2 * 16 + (l & 15);
                bf16x8 vf = *(const bf16x8*)((const char*)VT + dd * 128 +
                            ((s * 64 + (l >> 4) * 16) ^ ((dd & 7) << 4)));
                if (m2 == 0) acc0 = __builtin_amdgcn_mfma_f32_16x16x32_bf16(vf, pb.v, acc0, 0, 0, 0);
                else         acc1 = __builtin_amdgcn_mfma_f32_16x16x32_bf16(vf, pb.v, acc1, 0, 0, 0);
            }
        }
        if (kt < 14) { kvc = kvn; vvc = vvn; }
    }

    float inv = 1.0f / l_run;
    int q = qrow_w + (l & 15);
    if (q < LQ) {
        size_t obase = ((size_t)(b * LQ + q)) * 256 + h * 32;
#pragma unroll
        for (int r = 0; r < 4; ++r) {
            int d0 = (l >> 4) * 4 + r;
            outB[obase + d0]      = f2b(acc0[r] * inv);
            outB[obase + 16 + d0] = f2b(acc1[r] * inv);
        }
    }
}

// ---------------------------------------------------------------------------
// Fused: sampling-weight softmax + locations + bilinear sampling (r12).
// ---------------------------------------------------------------------------
__global__ __launch_bounds__(256) void sample_fused(
    const float* __restrict__ off_att, const float* __restrict__ refp,
    const unsigned short* __restrict__ val,
    const int* __restrict__ shapes, const int* __restrict__ starts,
    float* __restrict__ aw_out, float* __restrict__ loc_out,
    unsigned short* __restrict__ xs, int NV)
{
    const int row = blockIdx.x;
    const int b = row / LQ;
    const int t = threadIdx.x;
    const int h = t >> 5, d = t & 31;

    __shared__ float l_logit[128];
    __shared__ float l_aw[128];
    __shared__ float l_loc[256];
    __shared__ int l_sh[NL * 2];
    __shared__ int l_st[NL];

    if (t < 128) l_logit[t] = off_att[(size_t)row * 384 + 256 + t];
    {
        float o = off_att[(size_t)row * 384 + t];
        int c = t & 1;
        int lv = (t >> 3) & 3;
        float rc = refp[((size_t)row * 4 + lv) * 4 + c];
        float rs = refp[((size_t)row * 4 + lv) * 4 + 2 + c];
        float loc = rc + o * 0.125f * rs;
        l_loc[t] = loc;
        loc_out[(size_t)row * 256 + t] = loc;
    }
    if (t < NL * 2) l_sh[t] = shapes[t];
    if (t < NL) l_st[t] = starts[t];
    __syncthreads();
    if (t < 128) {
        int hh = t >> 4;
        float mx = -1e30f;
#pragma unroll
        for (int i = 0; i < 16; ++i) mx = fmaxf(mx, l_logit[hh * 16 + i]);
        float sum = 0.f;
#pragma unroll
        for (int i = 0; i < 16; ++i) sum += __expf(l_logit[hh * 16 + i] - mx);
        float aw = __expf(l_logit[t] - mx) / sum;
        l_aw[t] = aw;
        aw_out[(size_t)row * 128 + t] = aw;
    }
    __syncthreads();

    float acc = 0.f;
    const unsigned short* vb = val + (size_t)b * NV * EE + h * HD + d;

#pragma unroll
    for (int lv = 0; lv < NL; ++lv) {
        const int Hh = l_sh[lv * 2], Ww = l_sh[lv * 2 + 1];
        const int s0 = l_st[lv];
#pragma unroll
        for (int p = 0; p < NP; ++p) {
            const int base = ((h * NL + lv) * NP + p) * 2;
            float lx = l_loc[base], ly = l_loc[base + 1];
            float wgt0 = l_aw[h * 16 + lv * NP + p];
            float px = lx * (float)Ww - 0.5f;
            float py = ly * (float)Hh - 0.5f;
            float x0f = floorf(px), y0f = floorf(py);
            float wx = px - x0f, wy = py - y0f;
            int x0 = (int)x0f, y0 = (int)y0f;
#pragma unroll
            for (int dy = 0; dy < 2; ++dy) {
                int yi = y0 + dy;
                bool vy = (yi >= 0) && (yi < Hh);
                int yc = min(max(yi, 0), Hh - 1);
                float wyv = dy ? wy : 1.f - wy;
#pragma unroll
                for (int dx = 0; dx < 2; ++dx) {
                    int xi = x0 + dx;
                    bool vv = vy && (xi >= 0) && (xi < Ww);
                    int xc = min(max(xi, 0), Ww - 1);
                    float wgt = wgt0 * wyv * (dx ? wx : 1.f - wx);
                    float gv = b2f(vb[(size_t)(s0 + yc * Ww + xc) * EE]);
                    acc += vv ? wgt * gv : 0.f;
                }
            }
        }
    }
    xs[(size_t)row * 512 + 256 + t] = f2b(acc);
}

// ---------------------------------------------------------------------------
// Gated fusion + ln3 (unchanged).
// ---------------------------------------------------------------------------
__global__ __launch_bounds__(256) void gate_ln3(
    const float* __restrict__ g, const float* __restrict__ x1,
    const float* __restrict__ cross, const float* __restrict__ s,
    const float* __restrict__ bln, float* __restrict__ x2out,
    unsigned short* __restrict__ zb)
{
    const int row = blockIdx.x;
    const int t = threadIdx.x;
    const int w = t >> 6;
    const int lane = t & 63;
    __shared__ float red[4];

    float g1 = g[(size_t)row * 512 + t];
    float g2 = g[(size_t)row * 512 + 256 + t];
    float v = g1 * x1[(size_t)row * EE + t] + g2 * cross[(size_t)row * EE + t];
    x2out[(size_t)row * EE + t] = v;

    float sum = v;
#pragma unroll
    for (int o = 32; o; o >>= 1) sum += __shfl_xor(sum, o, 64);
    if (lane == 0) red[w] = sum;
    __syncthreads();
    float mean = (red[0] + red[1] + red[2] + red[3]) * (1.0f / 256.0f);
    __syncthreads();

    float d = v - mean;
    float sq = d * d;
#pragma unroll
    for (int o = 32; o; o >>= 1) sq += __shfl_xor(sq, o, 64);
    if (lane == 0) red[w] = sq;
    __syncthreads();
    float var = (red[0] + red[1] + red[2] + red[3]) * (1.0f / 256.0f);

    float y = d * rsqrtf(var + 1e-5f) * s[t] + bln[t];
    zb[(size_t)row * EE + t] = f2b(y);
}

// ---------------------------------------------------------------------------
extern "C" void kernel_launch(void* const* d_in, const int* in_sizes, int n_in,
                              void* d_out, int out_size, void* d_ws, size_t ws_size,
                              hipStream_t stream)
{
    const float* queries   = (const float*)d_in[0];
    const float* memory    = (const float*)d_in[1];
    const float* query_pos = (const float*)d_in[2];
    const float* refp      = (const float*)d_in[3];
    const int*   shapes    = (const int*)d_in[4];
    const int*   starts    = (const int*)d_in[5];
    const float* Wq  = (const float*)d_in[6],  *bq  = (const float*)d_in[7];
    const float* Wk  = (const float*)d_in[8],  *bk  = (const float*)d_in[9];
    const float* Wv  = (const float*)d_in[10], *bv  = (const float*)d_in[11];
    const float* Wo  = (const float*)d_in[12], *bo  = (const float*)d_in[13];
    const float* Wvd = (const float*)d_in[14], *bvd = (const float*)d_in[15];
    const float* Woff= (const float*)d_in[16], *boff= (const float*)d_in[17];
    const float* Watt= (const float*)d_in[18], *batt= (const float*)d_in[19];
    const float* Wop = (const float*)d_in[20], *bop = (const float*)d_in[21];
    const float* Wg  = (const float*)d_in[22], *bg  = (const float*)d_in[23];
    const float* W1  = (const float*)d_in[24], *b1  = (const float*)d_in[25];
    const float* W2  = (const float*)d_in[26], *b2  = (const float*)d_in[27];
    const float* ln1_s = (const float*)d_in[28], *ln1_b = (const float*)d_in[29];
    const float* ln2_s = (const float*)d_in[30], *ln2_b = (const float*)d_in[31];
    const float* ln3_s = (const float*)d_in[32], *ln3_b = (const float*)d_in[33];

    const int NV = in_sizes[1] / (BB * EE);   // 13294
    const int Mq = BB * LQ;                   // 7200
    const int Mv = BB * NV;                   // 106352
    const long memN = (long)Mv * EE;

    char* W8 = (char*)d_ws;
    size_t off = 0;
    auto alloc = [&](size_t bytes) { char* p = W8 + off; off += (bytes + 255) & ~(size_t)255; return p; };

    unsigned short* mem_b = (unsigned short*)alloc((size_t)memN * 2);
    unsigned short* val_b = (unsigned short*)alloc((size_t)memN * 2);
    unsigned short* WtQK  = (unsigned short*)alloc(512 * 256 * 2);
    unsigned short* WtV   = (unsigned short*)alloc(256 * 256 * 2);
    unsigned short* WtO   = (unsigned short*)alloc(256 * 256 * 2);
    unsigned short* WtVD  = (unsigned short*)alloc(256 * 256 * 2);
    unsigned short* WtOA  = (unsigned short*)alloc(384 * 256 * 2);
    unsigned short* WtOP  = (unsigned short*)alloc(256 * 256 * 2);
    unsigned short* WtGF  = (unsigned short*)alloc(512 * 512 * 2);
    unsigned short* Wg2T  = (unsigned short*)alloc(512 * 256 * 2);
    unsigned short* WopRow= (unsigned short*)alloc(256 * 256 * 2);
    unsigned short* Wt1   = (unsigned short*)alloc(1024 * 256 * 2);
    unsigned short* Wt2   = (unsigned short*)alloc(256 * 1024 * 2);
    float*          bqk   = (float*)alloc(512 * 4);
    float*          boa   = (float*)alloc(384 * 4);
    float*          bgg   = (float*)alloc(512 * 4);
    unsigned short* qkb   = (unsigned short*)alloc((size_t)Mq * 512 * 2);
    unsigned short* vb_buf= (unsigned short*)alloc((size_t)Mq * 256 * 2);
    unsigned short* av_buf= (unsigned short*)alloc((size_t)Mq * 256 * 2);
    float*          x1    = (float*)alloc((size_t)Mq * 256 * 4);
    unsigned short* xs_cat= (unsigned short*)alloc((size_t)Mq * 512 * 2);
    unsigned short* qc_b  = (unsigned short*)alloc((size_t)Mq * 256 * 2);
    unsigned short* qk_b  = (unsigned short*)alloc((size_t)Mq * 256 * 2);
    float*          cross = (float*)alloc((size_t)Mq * 256 * 4);

    unsigned short* x_b = (unsigned short*)cross;
    float* off_att = (float*)qkb;
    float* gbuf = (float*)mem_b;
    float* x2   = (float*)((char*)mem_b + (size_t)Mq * 512 * 4);
    unsigned short* z_b = (unsigned short*)((char*)x2 + (size_t)Mq * 256 * 4);
    unsigned short* hidden_b = (unsigned short*)((char*)z_b + (size_t)Mq * 256 * 2);

    float* out0    = (float*)d_out;
    float* aw_out  = out0 + (size_t)Mq * 256;
    float* loc_out = aw_out + (size_t)Mq * 128;

    dim3 blk(256);
    const int tMq = (Mq + 63) / 64;    // 113
    const int tv  = (Mv + 63) / 64;    // 1662

    // 1. prep
    TPack tp;
    tp.d[0]  = { Wq,             WtQK,             256, 256,    0 };
    tp.d[1]  = { Wk,             WtQK + 256 * 256, 256, 256,   64 };
    tp.d[2]  = { Wv,             WtV,              256, 256,  128 };
    tp.d[3]  = { Wo,             WtO,              256, 256,  192 };
    tp.d[4]  = { Wvd,            WtVD,             256, 256,  256 };
    tp.d[5]  = { Woff,           WtOA,             256, 256,  320 };
    tp.d[6]  = { Watt,           WtOA + 256 * 256, 256, 128,  384 };
    tp.d[7]  = { Wop,            WtOP,             256, 256,  416 };
    tp.d[8]  = { Wg,             WtGF,             512, 512,  480 };  // 128 tiles: Wg1^T
    tp.d[9]  = { Wg + 256 * 512, Wg2T,             256, 512,  608 };  // 128 tiles: Wg2^T
    tp.d[10] = { W1,             Wt1,              256, 1024, 736 };
    tp.d[11] = { W2,             Wt2,             1024, 256,  992 };
    tp.bq = bq; tp.bk = bk; tp.boff = boff; tp.batt = batt;
    tp.bqk = bqk; tp.boa = boa;
    tp.Wop_src = Wop; tp.Wg_src = Wg; tp.bop_src = bop; tp.bg_src = bg;
    tp.WopRow = WopRow; tp.bgg = bgg;
    prep_kernel<<<10534, blk, 0, stream>>>(
        tp, queries, query_pos, ln1_s, ln1_b, x_b, qk_b, memory, mem_b, memN);

    // 2. batched {VAL, QK, V, WopG} — persistent BM=64 x BN=128, ring-3
    {
        GB g; g.nd = 4;
        g.d[0] = { mem_b, WtVD, bvd, nullptr, nullptr, val_b,
                   nullptr, nullptr, nullptr, nullptr,
                   Mv, 256, 256, 2, 0, 256, 0, 0, 0 };
        g.d[1] = { qk_b, WtQK, bqk, nullptr, nullptr, qkb,
                   nullptr, nullptr, nullptr, nullptr,
                   Mq, 256, 512, 4, tv * 2, 512, 0, 0, 0 };
        g.d[2] = { x_b, WtV, bv, nullptr, nullptr, vb_buf,
                   nullptr, nullptr, nullptr, nullptr,
                   Mq, 256, 256, 2, tv * 2 + tMq * 4, 256, 0, 0, 0 };
        g.d[3] = { Wg2T, WopRow, nullptr, nullptr, nullptr, WtGF,
                   nullptr, nullptr, nullptr, nullptr,
                   512, 256, 256, 2, tv * 2 + tMq * 6, 512, 256, 0, 0 };
        g.tot = tv * 2 + tMq * 6 + 16;   // 4018
        gemm_pipe<128><<<1536, blk, 0, stream>>>(g);
    }

    // 3. self-attention
    attn_mfma<<<dim3(15, BB * NH), blk, 0, stream>>>(qkb, vb_buf, av_buf);

    // 4. x1 = attnV @ Wo + bo + queries; fused ln2(+pos) -> qc_b  (BN=256)
    {
        GB g; g.nd = 1;
        g.d[0] = { av_buf, WtO, bo, queries, x1, xs_cat,
                   ln2_s, ln2_b, query_pos, qc_b,
                   Mq, 256, 256, 1, 0, 512, 0, 0, 0 };
        g.tot = tMq;
        gemm_pipe<256><<<tMq, blk, 0, stream>>>(g);
    }

    // 5. off|att logits
    {
        GB g; g.nd = 1;
        g.d[0] = { qc_b, WtOA, boa, nullptr, off_att, nullptr,
                   nullptr, nullptr, nullptr, nullptr,
                   Mq, 256, 384, 3, 0, 384, 0, 0, 0 };
        g.tot = tMq * 3;
        gemm_pipe<128><<<g.tot, blk, 0, stream>>>(g);
    }

    // 6. softmax + loc + bilinear sampling -> xs_cat[:,256:]
    sample_fused<<<Mq, blk, 0, stream>>>(off_att, refp, val_b, shapes, starts,
                                         aw_out, loc_out, xs_cat, NV);

    // 7. batched { cross, g=sigmoid([x1|samp]@WtGF+bgg) }
    {
        GB g; g.nd = 2;
        g.d[0] = { xs_cat + 256, WtOP, bop, nullptr, cross, nullptr,
                   nullptr, nullptr, nullptr, nullptr,
                   Mq, 256, 256, 2, 0, 0, 0, 0, 512 };
        g.d[1] = { xs_cat, WtGF, bgg, nullptr, gbuf, nullptr,
                   nullptr, nullptr, nullptr, nullptr,
                   Mq, 512, 512, 4, tMq * 2, 0, 0, 2, 0 };
        g.tot = tMq * 6;
        gemm_pipe<128><<<g.tot, blk, 0, stream>>>(g);
    }

    // 8. x2 + ln3
    gate_ln3<<<Mq, blk, 0, stream>>>(gbuf, x1, cross, ln3_s, ln3_b, x2, z_b);

    // 9. hidden = relu(z @ W1 + b1)
    {
        GB g; g.nd = 1;
        g.d[0] = { z_b, Wt1, b1, nullptr, nullptr, hidden_b,
                   nullptr, nullptr, nullptr, nullptr,
                   Mq, 256, 1024, 8, 0, 1024, 0, 1, 0 };
        g.tot = tMq * 8;
        gemm_pipe<128><<<g.tot, blk, 0, stream>>>(g);
    }

    // 10. out0 = hidden @ W2 + b2 + x2
    {
        GB g; g.nd = 1;
        g.d[0] = { hidden_b, Wt2, b2, x2, out0, nullptr,
                   nullptr, nullptr, nullptr, nullptr,
                   Mq, 1024, 256, 2, 0, 256, 0, 0, 0 };
        g.tot = tMq * 2;
        gemm_pipe<128><<<g.tot, blk, 0, stream>>>(g);
    }
}

// Round 15
// 303.851 us; speedup vs baseline: 1.2154x; 1.1401x over previous
//
#include <hip/hip_runtime.h>
#include <hip/hip_bf16.h>
#include <math.h>

#define BB 8
#define LQ 900
#define EE 256
#define NH 8
#define HD 32
#define NL 4
#define NP 4
#define FFN_H 1024

typedef __bf16 bf16x8 __attribute__((ext_vector_type(8)));
typedef float f32x4 __attribute__((ext_vector_type(4)));
typedef unsigned short u16x8 __attribute__((ext_vector_type(8)));

__device__ __forceinline__ unsigned short f2b(float f) {
    union { float f; unsigned int u; } v; v.f = f;
    unsigned int u = v.u;
    unsigned int r = (u + 0x7fffu + ((u >> 16) & 1u)) >> 16;
    return (unsigned short)r;
}
__device__ __forceinline__ float b2f(unsigned short h) {
    union { unsigned int u; float f; } v; v.u = ((unsigned int)h) << 16; return v.f;
}

typedef __attribute__((address_space(3))) unsigned int* lds_ptr_t;
typedef const __attribute__((address_space(1))) unsigned int* gbl_ptr_t;
#define GLOAD16(g, l) __builtin_amdgcn_global_load_lds((gbl_ptr_t)(g), (lds_ptr_t)(l), 16, 0, 0)
#define VMCNT(n) asm volatile("s_waitcnt vmcnt(" #n ")" ::: "memory")

// ---------------------------------------------------------------------------
// prep block map (identical to r12, passed):
//   [0,1248) weight transpose | [1248,1252) bias concat | [1252,1284) WopRow
//   [1284,1286) bgg | [1286,8486) ln1 | [8486,10534) memory cast
// ---------------------------------------------------------------------------
struct TDesc { const float* src; unsigned short* dst; int K, N, tile0; };
struct TPack {
    TDesc d[12];
    const float *bq, *bk, *boff, *batt;
    float *bqk, *boa;
    const float *Wop_src, *Wg_src, *bop_src, *bg_src;
    unsigned short* WopRow;
    float* bgg;
};

__global__ __launch_bounds__(256) void prep_kernel(
    TPack p,
    const float* __restrict__ queries, const float* __restrict__ qpos,
    const float* __restrict__ ln1_s, const float* __restrict__ ln1_b,
    unsigned short* __restrict__ x_b, unsigned short* __restrict__ qk_b,
    const float* __restrict__ mem, unsigned short* __restrict__ mem_b, long memN)
{
    const int bi = blockIdx.x;
    const int t = threadIdx.x;

    if (bi < 1248) {
        int di = 0;
#pragma unroll
        for (int i = 1; i < 12; ++i) if (bi >= p.d[i].tile0) di = i;
        TDesc d = p.d[di];
        int tt = bi - d.tile0;
        int tn = (d.N + 31) >> 5;
        int tk = tt / tn, tc = tt % tn;
        __shared__ float tile[32][33];
        int tx = t & 31, ty = t >> 5;
#pragma unroll
        for (int i = 0; i < 4; ++i) {
            int kk = tk * 32 + ty + i * 8, nn = tc * 32 + tx;
            tile[ty + i * 8][tx] = d.src[(size_t)kk * d.N + nn];
        }
        __syncthreads();
#pragma unroll
        for (int i = 0; i < 4; ++i) {
            int nn = tc * 32 + ty + i * 8, kk = tk * 32 + tx;
            d.dst[(size_t)nn * d.K + kk] = f2b(tile[tx][ty + i * 8]);
        }
        return;
    }
    if (bi < 1252) {
        int which = bi - 1248;
        if (which == 0)      p.bqk[t] = p.bq[t];
        else if (which == 1) p.bqk[256 + t] = p.bk[t];
        else if (which == 2) p.boa[t] = p.boff[t];
        else if (t < 128)    p.boa[256 + t] = p.batt[t];
        return;
    }
    if (bi < 1284) {
        long i = ((long)(bi - 1252) * 256 + t) * 8;
        float4 a = *(const float4*)(p.Wop_src + i);
        float4 b = *(const float4*)(p.Wop_src + i + 4);
        u16x8 o;
        o[0] = f2b(a.x); o[1] = f2b(a.y); o[2] = f2b(a.z); o[3] = f2b(a.w);
        o[4] = f2b(b.x); o[5] = f2b(b.y); o[6] = f2b(b.z); o[7] = f2b(b.w);
        *(u16x8*)(p.WopRow + i) = o;
        return;
    }
    if (bi < 1286) {
        int n = (bi - 1284) * 256 + t;
        float bb = p.bg_src[n];
        for (int j = 0; j < 256; ++j)
            bb += p.bop_src[j] * p.Wg_src[(size_t)(256 + j) * 512 + n];
        p.bgg[n] = bb;
        return;
    }
    if (bi < 8486) {
        const int row = bi - 1286;
        const int w = t >> 6, lane = t & 63;
        __shared__ float red[4];
        float v = queries[(size_t)row * EE + t];
        float sum = v;
#pragma unroll
        for (int o = 32; o; o >>= 1) sum += __shfl_xor(sum, o, 64);
        if (lane == 0) red[w] = sum;
        __syncthreads();
        float mean = (red[0] + red[1] + red[2] + red[3]) * (1.0f / 256.0f);
        __syncthreads();
        float dd = v - mean;
        float sq = dd * dd;
#pragma unroll
        for (int o = 32; o; o >>= 1) sq += __shfl_xor(sq, o, 64);
        if (lane == 0) red[w] = sq;
        __syncthreads();
        float var = (red[0] + red[1] + red[2] + red[3]) * (1.0f / 256.0f);
        float y = dd * rsqrtf(var + 1e-5f) * ln1_s[t] + ln1_b[t];
        x_b[(size_t)row * EE + t]  = f2b(y);
        qk_b[(size_t)row * EE + t] = f2b(y + qpos[(size_t)row * EE + t]);
        return;
    }
    {
        long i = ((long)(bi - 8486) * 256 + t) * 8;
        long stride = (long)2048 * 256 * 8;
        for (; i < memN; i += stride) {
            float4 a = *(const float4*)(mem + i);
            float4 b = *(const float4*)(mem + i + 4);
            u16x8 o;
            o[0] = f2b(a.x); o[1] = f2b(a.y); o[2] = f2b(a.z); o[3] = f2b(a.w);
            o[4] = f2b(b.x); o[5] = f2b(b.y); o[6] = f2b(b.z); o[7] = f2b(b.w);
            *(u16x8*)(mem_b + i) = o;
        }
    }
}

// ---------------------------------------------------------------------------
// Batched persistent pipelined bf16 MFMA GEMM (r12-proven, 2-buffer).
// BM=64, template BN; runtime ldA (0 => K). BN=256: fused row-LN epilogue.
// ---------------------------------------------------------------------------
struct GD {
    const unsigned short* A;
    const unsigned short* Bt;
    const float* bias;
    const float* resid;
    float* outF;
    unsigned short* outB;
    const float* lnS; const float* lnB; const float* lnAdd;
    unsigned short* lnOut;
    int M, K, N, ntN, tile0, ldOutB, outBoff, act, ldA;
};
struct GB { GD d[3]; int nd, tot; };

template<int BN>
__global__ __launch_bounds__(256, (BN == 128) ? 4 : 2) void gemm_pipe(GB g) {
    __shared__ __align__(16) unsigned short ldsb[2][(64 + BN) * 32];
    __shared__ float lnred[2][64][2];
    const int tid = threadIdx.x;
    const int l = tid & 63, w = tid >> 6;
    const int wr = w >> 1, wc = w & 1;
    constexpr int NJ = BN / 32;

    int t = blockIdx.x;
    if (t >= g.tot) return;
    int d = 0;
    while (d + 1 < g.nd && t >= g.d[d + 1].tile0) ++d;

    auto stage = [&](int dd, int tt, int ks, int pp) {
        const GD& D = g.d[dd];
        const int lda = D.ldA ? D.ldA : D.K;
        int local = tt - D.tile0;
        int m0 = (local / D.ntN) * 64;
        int n0 = (local % D.ntN) * BN;
        unsigned short* base = &ldsb[pp][0];
        {
            int row = w * 16 + (l >> 2);
            int rg = m0 + row; int mm = D.M - 1; rg = rg < mm ? rg : mm;
            int schunk = ((l & 3) ^ ((row >> 1) & 3)) << 4;
            GLOAD16((const char*)(D.A + (size_t)rg * lda + (ks << 5)) + schunk,
                    base + (w * 16) * 32);
        }
#pragma unroll
        for (int ib = 0; ib < BN / 64; ++ib) {
            int row = ib * 64 + w * 16 + (l >> 2);
            int rg = n0 + row; int nn = D.N - 1; rg = rg < nn ? rg : nn;
            int schunk = ((l & 3) ^ ((row >> 1) & 3)) << 4;
            GLOAD16((const char*)(D.Bt + (size_t)rg * D.K + (ks << 5)) + schunk,
                    base + 2048 + (ib * 64 + w * 16) * 32);
        }
    };

    stage(d, t, 0, 0);
    int p = 0;

    while (true) {
        const GD D = g.d[d];
        int local = t - D.tile0;
        const int m0 = (local / D.ntN) * 64;
        const int n0 = (local % D.ntN) * BN;
        const int nk = D.K >> 5;

        f32x4 acc[2][NJ];
#pragma unroll
        for (int i = 0; i < 2; ++i)
#pragma unroll
            for (int j = 0; j < NJ; ++j) acc[i][j] = (f32x4){0.f, 0.f, 0.f, 0.f};

        for (int ks = 0; ks < nk; ++ks) {
            int nt = t, nks = ks + 1, ndd = d;
            bool have = true;
            if (nks == nk) {
                nt = t + gridDim.x; nks = 0;
                if (nt >= g.tot) have = false;
                else { while (ndd + 1 < g.nd && nt >= g.d[ndd + 1].tile0) ++ndd; }
            }
            if (have) {
                stage(ndd, nt, nks, p ^ 1);
                if constexpr (BN == 128) { VMCNT(3); } else { VMCNT(5); }
            } else {
                VMCNT(0);
            }
            __builtin_amdgcn_sched_barrier(0);
            __builtin_amdgcn_s_barrier();
            __builtin_amdgcn_sched_barrier(0);
            {
                const char* base = (const char*)&ldsb[p][0];
                const int rch = ((l >> 4) ^ ((l >> 1) & 3)) << 4;
                bf16x8 af[2];
#pragma unroll
                for (int i = 0; i < 2; ++i) {
                    int row = wr * 32 + i * 16 + (l & 15);
                    af[i] = *(const bf16x8*)(base + row * 64 + rch);
                }
#pragma unroll
                for (int j = 0; j < NJ; ++j) {
                    int row = wc * (BN / 2) + j * 16 + (l & 15);
                    bf16x8 bfr = *(const bf16x8*)(base + 4096 + row * 64 + rch);
#pragma unroll
                    for (int i = 0; i < 2; ++i)
                        acc[i][j] = __builtin_amdgcn_mfma_f32_16x16x32_bf16(af[i], bfr, acc[i][j], 0, 0, 0);
                }
            }
            __builtin_amdgcn_sched_barrier(0);
            __builtin_amdgcn_s_barrier();
            __builtin_amdgcn_sched_barrier(0);
            p ^= 1;
        }

        // epilogue
#pragma unroll
        for (int i = 0; i < 2; ++i) {
#pragma unroll
            for (int r = 0; r < 4; ++r) {
                int gm = m0 + wr * 32 + i * 16 + ((l >> 4) << 2) + r;
                if (gm >= D.M) continue;
#pragma unroll
                for (int j = 0; j < NJ; ++j) {
                    int gn = n0 + wc * (BN / 2) + j * 16 + (l & 15);
                    if (gn >= D.N) continue;
                    float v = acc[i][j][r];
                    if (D.bias)  v += D.bias[gn];
                    if (D.resid) v += D.resid[(size_t)gm * D.N + gn];
                    if (D.act == 1)      v = fmaxf(v, 0.f);
                    else if (D.act == 2) v = 1.0f / (1.0f + __expf(-v));
                    acc[i][j][r] = v;
                    if (D.outF) D.outF[(size_t)gm * D.N + gn] = v;
                    if (D.outB) D.outB[(size_t)gm * D.ldOutB + D.outBoff + gn] = f2b(v);
                }
            }
        }

        if constexpr (BN == 256) {
            if (D.lnOut) {
#pragma unroll
                for (int i = 0; i < 2; ++i) {
#pragma unroll
                    for (int r = 0; r < 4; ++r) {
                        float s1 = 0.f, s2 = 0.f;
#pragma unroll
                        for (int j = 0; j < NJ; ++j) {
                            float v = acc[i][j][r];
                            s1 += v; s2 += v * v;
                        }
#pragma unroll
                        for (int o = 1; o <= 8; o <<= 1) {
                            s1 += __shfl_xor(s1, o, 64);
                            s2 += __shfl_xor(s2, o, 64);
                        }
                        if ((l & 15) == 0) {
                            int row = wr * 32 + i * 16 + ((l >> 4) << 2) + r;
                            lnred[wc][row][0] = s1;
                            lnred[wc][row][1] = s2;
                        }
                    }
                }
                __syncthreads();
#pragma unroll
                for (int i = 0; i < 2; ++i) {
#pragma unroll
                    for (int r = 0; r < 4; ++r) {
                        int row = wr * 32 + i * 16 + ((l >> 4) << 2) + r;
                        int gm = m0 + row;
                        if (gm >= D.M) continue;
                        float mean = (lnred[0][row][0] + lnred[1][row][0]) * (1.0f / 256.0f);
                        float msq  = (lnred[0][row][1] + lnred[1][row][1]) * (1.0f / 256.0f);
                        float rs = rsqrtf(msq - mean * mean + 1e-5f);
#pragma unroll
                        for (int j = 0; j < NJ; ++j) {
                            int gn = wc * 128 + j * 16 + (l & 15);
                            float y = (acc[i][j][r] - mean) * rs * D.lnS[gn] + D.lnB[gn]
                                      + D.lnAdd[(size_t)gm * 256 + gn];
                            D.lnOut[(size_t)gm * 256 + gn] = f2b(y);
                        }
                    }
                }
            }
        }

        t += gridDim.x;
        if (t >= g.tot) break;
        while (d + 1 < g.nd && t >= g.d[d + 1].tile0) ++d;
    }
}

// ---------------------------------------------------------------------------
// Co-resident kernel: blocks [0,960) run flash self-attention (r12 code,
// 1D-decoded); blocks [960, 960+VGRID) run the val GEMM persistent tile
// loop (r12 batch descriptor 0). Shared LDS arena aliased by branch.
// ---------------------------------------------------------------------------
#define VGRID 1536

__global__ __launch_bounds__(256) void attn_val(
    const unsigned short* __restrict__ QK, const unsigned short* __restrict__ Vb,
    unsigned short* __restrict__ outB,
    const unsigned short* __restrict__ vA, const unsigned short* __restrict__ vBt,
    const float* __restrict__ vbias, unsigned short* __restrict__ vout,
    int Mv, int vtiles)
{
    __shared__ __align__(16) unsigned short smem[(64 + 128) * 32 * 2];  // 24576 B
    const int bid = blockIdx.x;
    const int tid = threadIdx.x;
    const int l = tid & 63, w = tid >> 6;

    if (bid >= 960) {
        // ---- val GEMM: C[Mv,256] = A[Mv,256] @ Bt[256,256]^T + bias ----
        const int wr = w >> 1, wc = w & 1;
        int t = bid - 960;
        if (t >= vtiles) return;

        auto stage = [&](int tt, int ks, int pp) {
            unsigned short* base = &smem[pp * 192 * 32];
            int m0 = (tt >> 1) * 64;
            int n0 = (tt & 1) * 128;
            {
                int row = w * 16 + (l >> 2);
                int rg = m0 + row; int mm = Mv - 1; rg = rg < mm ? rg : mm;
                int schunk = ((l & 3) ^ ((row >> 1) & 3)) << 4;
                GLOAD16((const char*)(vA + (size_t)rg * 256 + (ks << 5)) + schunk,
                        base + (w * 16) * 32);
            }
#pragma unroll
            for (int ib = 0; ib < 2; ++ib) {
                int row = ib * 64 + w * 16 + (l >> 2);
                int rg = n0 + row;
                int schunk = ((l & 3) ^ ((row >> 1) & 3)) << 4;
                GLOAD16((const char*)(vBt + (size_t)rg * 256 + (ks << 5)) + schunk,
                        base + 2048 + (ib * 64 + w * 16) * 32);
            }
        };

        stage(t, 0, 0);
        int p = 0;
        while (true) {
            const int m0 = (t >> 1) * 64;
            const int n0 = (t & 1) * 128;

            f32x4 acc[2][4];
#pragma unroll
            for (int i = 0; i < 2; ++i)
#pragma unroll
                for (int j = 0; j < 4; ++j) acc[i][j] = (f32x4){0.f, 0.f, 0.f, 0.f};

            for (int ks = 0; ks < 8; ++ks) {
                int nt = t, nks = ks + 1;
                bool have = true;
                if (nks == 8) {
                    nt = t + VGRID; nks = 0;
                    if (nt >= vtiles) have = false;
                }
                if (have) { stage(nt, nks, p ^ 1); VMCNT(3); }
                else      { VMCNT(0); }
                __builtin_amdgcn_sched_barrier(0);
                __builtin_amdgcn_s_barrier();
                __builtin_amdgcn_sched_barrier(0);
                {
                    const char* base = (const char*)&smem[p * 192 * 32];
                    const int rch = ((l >> 4) ^ ((l >> 1) & 3)) << 4;
                    bf16x8 af[2];
#pragma unroll
                    for (int i = 0; i < 2; ++i) {
                        int row = wr * 32 + i * 16 + (l & 15);
                        af[i] = *(const bf16x8*)(base + row * 64 + rch);
                    }
#pragma unroll
                    for (int j = 0; j < 4; ++j) {
                        int row = wc * 64 + j * 16 + (l & 15);
                        bf16x8 bfr = *(const bf16x8*)(base + 4096 + row * 64 + rch);
#pragma unroll
                        for (int i = 0; i < 2; ++i)
                            acc[i][j] = __builtin_amdgcn_mfma_f32_16x16x32_bf16(af[i], bfr, acc[i][j], 0, 0, 0);
                    }
                }
                __builtin_amdgcn_sched_barrier(0);
                __builtin_amdgcn_s_barrier();
                __builtin_amdgcn_sched_barrier(0);
                p ^= 1;
            }

#pragma unroll
            for (int i = 0; i < 2; ++i) {
#pragma unroll
                for (int r = 0; r < 4; ++r) {
                    int gm = m0 + wr * 32 + i * 16 + ((l >> 4) << 2) + r;
                    if (gm >= Mv) continue;
#pragma unroll
                    for (int j = 0; j < 4; ++j) {
                        int gn = n0 + wc * 64 + j * 16 + (l & 15);
                        float v = acc[i][j][r] + vbias[gn];
                        vout[(size_t)gm * 256 + gn] = f2b(v);
                    }
                }
            }

            t += VGRID;
            if (t >= vtiles) break;
        }
        return;
    }

    // ---- attention: bid in [0,960), qt = bid % 15, bh = bid / 15 ----
    const int qt = bid % 15;
    const int bh = bid / 15;
    const int b = bh >> 3, h = bh & 7;

    unsigned short* Ks = smem;              // [64*32]
    unsigned short* VT = smem + 2048;       // [32*64]
    unsigned short* Ps = smem + 4096;       // [4][64*20] = 5120 elems

    const int qrow_w = qt * 64 + w * 16;
    int qr = qrow_w + (l & 15); qr = qr < LQ ? qr : LQ - 1;
    bf16x8 qf = *(const bf16x8*)(QK + ((size_t)(b * LQ + qr)) * 512 + h * 32 + (l >> 4) * 8);

    f32x4 acc0 = {0.f, 0.f, 0.f, 0.f}, acc1 = {0.f, 0.f, 0.f, 0.f};
    float m_run = -1e30f, l_run = 0.f;
    const float scale = 0.17677669529663689f;
    const f32x4 z4 = {0.f, 0.f, 0.f, 0.f};

    const int key = tid >> 2;
    const int dg = (tid & 3) * 8;
    u16x8 kvc, vvc, kvn, vvn;
    {
        int krow = key; krow = krow < LQ ? krow : LQ - 1;
        size_t base = (size_t)(b * LQ + krow);
        kvc = *(const u16x8*)(QK + base * 512 + 256 + h * 32 + dg);
        vvc = *(const u16x8*)(Vb + base * 256 + h * 32 + dg);
    }

    for (int kt = 0; kt < 15; ++kt) {
        __syncthreads();
        *(u16x8*)((char*)Ks + key * 64 + ((dg * 2) ^ ((key & 3) << 4))) = kvc;
#pragma unroll
        for (int e = 0; e < 8; ++e) {
            int dd = dg + e;
            *(unsigned short*)((char*)VT + dd * 128 + ((key * 2) ^ ((dd & 7) << 4))) = vvc[e];
        }
        if (kt < 14) {
            int krow = (kt + 1) * 64 + key; krow = krow < LQ ? krow : LQ - 1;
            size_t base = (size_t)(b * LQ + krow);
            kvn = *(const u16x8*)(QK + base * 512 + 256 + h * 32 + dg);
            vvn = *(const u16x8*)(Vb + base * 256 + h * 32 + dg);
        }
        __syncthreads();

        float pv[4][4];
        float tmax = -1e30f;
#pragma unroll
        for (int m = 0; m < 4; ++m) {
            int kr = m * 16 + (l & 15);
            bf16x8 kf = *(const bf16x8*)((const char*)Ks + kr * 64 +
                        (((l >> 4) * 16) ^ ((kr & 3) << 4)));
            f32x4 sf = __builtin_amdgcn_mfma_f32_16x16x32_bf16(kf, qf, z4, 0, 0, 0);
#pragma unroll
            for (int r = 0; r < 4; ++r) {
                int kk = kt * 64 + m * 16 + (l >> 4) * 4 + r;
                float sv = (kk < LQ) ? sf[r] * scale : -1e30f;
                pv[m][r] = sv;
                tmax = fmaxf(tmax, sv);
            }
        }
        tmax = fmaxf(tmax, __shfl_xor(tmax, 16, 64));
        tmax = fmaxf(tmax, __shfl_xor(tmax, 32, 64));
        float newm = fmaxf(m_run, tmax);
        float corr = __expf(m_run - newm);
        m_run = newm;
        float tsum = 0.f;
#pragma unroll
        for (int m = 0; m < 4; ++m)
#pragma unroll
            for (int r = 0; r < 4; ++r) {
                float e = __expf(pv[m][r] - newm);
                pv[m][r] = e;
                tsum += e;
            }
        tsum += __shfl_xor(tsum, 16, 64);
        tsum += __shfl_xor(tsum, 32, 64);
        l_run = l_run * corr + tsum;
        acc0 *= corr;
        acc1 *= corr;

        unsigned short* pw = Ps + w * 1280;
#pragma unroll
        for (int m = 0; m < 4; ++m)
#pragma unroll
            for (int r = 0; r < 4; ++r) {
                int kk = m * 16 + (l >> 4) * 4 + r;
                pw[kk * 20 + (l & 15)] = f2b(pv[m][r]);
            }

#pragma unroll
        for (int s = 0; s < 2; ++s) {
            union { unsigned short u[8]; bf16x8 v; } pb;
#pragma unroll
            for (int j = 0; j < 8; ++j)
                pb.u[j] = pw[(s * 32 + (l >> 4) * 8 + j) * 20 + (l & 15)];
#pragma unroll
            for (int m2 = 0; m2 < 2; ++m2) {
                int dd = m2 * 16 + (l & 15);
                bf16x8 vf = *(const bf16x8*)((const char*)VT + dd * 128 +
                            ((s * 64 + (l >> 4) * 16) ^ ((dd & 7) << 4)));
                if (m2 == 0) acc0 = __builtin_amdgcn_mfma_f32_16x16x32_bf16(vf, pb.v, acc0, 0, 0, 0);
                else         acc1 = __builtin_amdgcn_mfma_f32_16x16x32_bf16(vf, pb.v, acc1, 0, 0, 0);
            }
        }
        if (kt < 14) { kvc = kvn; vvc = vvn; }
    }

    float inv = 1.0f / l_run;
    int q = qrow_w + (l & 15);
    if (q < LQ) {
        size_t obase = ((size_t)(b * LQ + q)) * 256 + h * 32;
#pragma unroll
        for (int r = 0; r < 4; ++r) {
            int d0 = (l >> 4) * 4 + r;
            outB[obase + d0]      = f2b(acc0[r] * inv);
            outB[obase + 16 + d0] = f2b(acc1[r] * inv);
        }
    }
}

// ---------------------------------------------------------------------------
// Fused: sampling-weight softmax + locations + bilinear sampling (r12).
// ---------------------------------------------------------------------------
__global__ __launch_bounds__(256) void sample_fused(
    const float* __restrict__ off_att, const float* __restrict__ refp,
    const unsigned short* __restrict__ val,
    const int* __restrict__ shapes, const int* __restrict__ starts,
    float* __restrict__ aw_out, float* __restrict__ loc_out,
    unsigned short* __restrict__ xs, int NV)
{
    const int row = blockIdx.x;
    const int b = row / LQ;
    const int t = threadIdx.x;
    const int h = t >> 5, d = t & 31;

    __shared__ float l_logit[128];
    __shared__ float l_aw[128];
    __shared__ float l_loc[256];
    __shared__ int l_sh[NL * 2];
    __shared__ int l_st[NL];

    if (t < 128) l_logit[t] = off_att[(size_t)row * 384 + 256 + t];
    {
        float o = off_att[(size_t)row * 384 + t];
        int c = t & 1;
        int lv = (t >> 3) & 3;
        float rc = refp[((size_t)row * 4 + lv) * 4 + c];
        float rs = refp[((size_t)row * 4 + lv) * 4 + 2 + c];
        float loc = rc + o * 0.125f * rs;
        l_loc[t] = loc;
        loc_out[(size_t)row * 256 + t] = loc;
    }
    if (t < NL * 2) l_sh[t] = shapes[t];
    if (t < NL) l_st[t] = starts[t];
    __syncthreads();
    if (t < 128) {
        int hh = t >> 4;
        float mx = -1e30f;
#pragma unroll
        for (int i = 0; i < 16; ++i) mx = fmaxf(mx, l_logit[hh * 16 + i]);
        float sum = 0.f;
#pragma unroll
        for (int i = 0; i < 16; ++i) sum += __expf(l_logit[hh * 16 + i] - mx);
        float aw = __expf(l_logit[t] - mx) / sum;
        l_aw[t] = aw;
        aw_out[(size_t)row * 128 + t] = aw;
    }
    __syncthreads();

    float acc = 0.f;
    const unsigned short* vb = val + (size_t)b * NV * EE + h * HD + d;

#pragma unroll
    for (int lv = 0; lv < NL; ++lv) {
        const int Hh = l_sh[lv * 2], Ww = l_sh[lv * 2 + 1];
        const int s0 = l_st[lv];
#pragma unroll
        for (int p = 0; p < NP; ++p) {
            const int base = ((h * NL + lv) * NP + p) * 2;
            float lx = l_loc[base], ly = l_loc[base + 1];
            float wgt0 = l_aw[h * 16 + lv * NP + p];
            float px = lx * (float)Ww - 0.5f;
            float py = ly * (float)Hh - 0.5f;
            float x0f = floorf(px), y0f = floorf(py);
            float wx = px - x0f, wy = py - y0f;
            int x0 = (int)x0f, y0 = (int)y0f;
#pragma unroll
            for (int dy = 0; dy < 2; ++dy) {
                int yi = y0 + dy;
                bool vy = (yi >= 0) && (yi < Hh);
                int yc = min(max(yi, 0), Hh - 1);
                float wyv = dy ? wy : 1.f - wy;
#pragma unroll
                for (int dx = 0; dx < 2; ++dx) {
                    int xi = x0 + dx;
                    bool vv = vy && (xi >= 0) && (xi < Ww);
                    int xc = min(max(xi, 0), Ww - 1);
                    float wgt = wgt0 * wyv * (dx ? wx : 1.f - wx);
                    float gv = b2f(vb[(size_t)(s0 + yc * Ww + xc) * EE]);
                    acc += vv ? wgt * gv : 0.f;
                }
            }
        }
    }
    xs[(size_t)row * 512 + 256 + t] = f2b(acc);
}

// ---------------------------------------------------------------------------
// Gated fusion + ln3 (unchanged).
// ---------------------------------------------------------------------------
__global__ __launch_bounds__(256) void gate_ln3(
    const float* __restrict__ g, const float* __restrict__ x1,
    const float* __restrict__ cross, const float* __restrict__ s,
    const float* __restrict__ bln, float* __restrict__ x2out,
    unsigned short* __restrict__ zb)
{
    const int row = blockIdx.x;
    const int t = threadIdx.x;
    const int w = t >> 6;
    const int lane = t & 63;
    __shared__ float red[4];

    float g1 = g[(size_t)row * 512 + t];
    float g2 = g[(size_t)row * 512 + 256 + t];
    float v = g1 * x1[(size_t)row * EE + t] + g2 * cross[(size_t)row * EE + t];
    x2out[(size_t)row * EE + t] = v;

    float sum = v;
#pragma unroll
    for (int o = 32; o; o >>= 1) sum += __shfl_xor(sum, o, 64);
    if (lane == 0) red[w] = sum;
    __syncthreads();
    float mean = (red[0] + red[1] + red[2] + red[3]) * (1.0f / 256.0f);
    __syncthreads();

    float d = v - mean;
    float sq = d * d;
#pragma unroll
    for (int o = 32; o; o >>= 1) sq += __shfl_xor(sq, o, 64);
    if (lane == 0) red[w] = sq;
    __syncthreads();
    float var = (red[0] + red[1] + red[2] + red[3]) * (1.0f / 256.0f);

    float y = d * rsqrtf(var + 1e-5f) * s[t] + bln[t];
    zb[(size_t)row * EE + t] = f2b(y);
}

// ---------------------------------------------------------------------------
extern "C" void kernel_launch(void* const* d_in, const int* in_sizes, int n_in,
                              void* d_out, int out_size, void* d_ws, size_t ws_size,
                              hipStream_t stream)
{
    const float* queries   = (const float*)d_in[0];
    const float* memory    = (const float*)d_in[1];
    const float* query_pos = (const float*)d_in[2];
    const float* refp      = (const float*)d_in[3];
    const int*   shapes    = (const int*)d_in[4];
    const int*   starts    = (const int*)d_in[5];
    const float* Wq  = (const float*)d_in[6],  *bq  = (const float*)d_in[7];
    const float* Wk  = (const float*)d_in[8],  *bk  = (const float*)d_in[9];
    const float* Wv  = (const float*)d_in[10], *bv  = (const float*)d_in[11];
    const float* Wo  = (const float*)d_in[12], *bo  = (const float*)d_in[13];
    const float* Wvd = (const float*)d_in[14], *bvd = (const float*)d_in[15];
    const float* Woff= (const float*)d_in[16], *boff= (const float*)d_in[17];
    const float* Watt= (const float*)d_in[18], *batt= (const float*)d_in[19];
    const float* Wop = (const float*)d_in[20], *bop = (const float*)d_in[21];
    const float* Wg  = (const float*)d_in[22], *bg  = (const float*)d_in[23];
    const float* W1  = (const float*)d_in[24], *b1  = (const float*)d_in[25];
    const float* W2  = (const float*)d_in[26], *b2  = (const float*)d_in[27];
    const float* ln1_s = (const float*)d_in[28], *ln1_b = (const float*)d_in[29];
    const float* ln2_s = (const float*)d_in[30], *ln2_b = (const float*)d_in[31];
    const float* ln3_s = (const float*)d_in[32], *ln3_b = (const float*)d_in[33];

    const int NV = in_sizes[1] / (BB * EE);   // 13294
    const int Mq = BB * LQ;                   // 7200
    const int Mv = BB * NV;                   // 106352
    const long memN = (long)Mv * EE;

    char* W8 = (char*)d_ws;
    size_t off = 0;
    auto alloc = [&](size_t bytes) { char* p = W8 + off; off += (bytes + 255) & ~(size_t)255; return p; };

    unsigned short* mem_b = (unsigned short*)alloc((size_t)memN * 2);
    unsigned short* val_b = (unsigned short*)alloc((size_t)memN * 2);
    unsigned short* WtQK  = (unsigned short*)alloc(512 * 256 * 2);
    unsigned short* WtV   = (unsigned short*)alloc(256 * 256 * 2);
    unsigned short* WtO   = (unsigned short*)alloc(256 * 256 * 2);
    unsigned short* WtVD  = (unsigned short*)alloc(256 * 256 * 2);
    unsigned short* WtOA  = (unsigned short*)alloc(384 * 256 * 2);
    unsigned short* WtOP  = (unsigned short*)alloc(256 * 256 * 2);
    unsigned short* WtGF  = (unsigned short*)alloc(512 * 512 * 2);
    unsigned short* Wg2T  = (unsigned short*)alloc(512 * 256 * 2);
    unsigned short* WopRow= (unsigned short*)alloc(256 * 256 * 2);
    unsigned short* Wt1   = (unsigned short*)alloc(1024 * 256 * 2);
    unsigned short* Wt2   = (unsigned short*)alloc(256 * 1024 * 2);
    float*          bqk   = (float*)alloc(512 * 4);
    float*          boa   = (float*)alloc(384 * 4);
    float*          bgg   = (float*)alloc(512 * 4);
    unsigned short* qkb   = (unsigned short*)alloc((size_t)Mq * 512 * 2);
    unsigned short* vb_buf= (unsigned short*)alloc((size_t)Mq * 256 * 2);
    unsigned short* av_buf= (unsigned short*)alloc((size_t)Mq * 256 * 2);
    float*          x1    = (float*)alloc((size_t)Mq * 256 * 4);
    unsigned short* xs_cat= (unsigned short*)alloc((size_t)Mq * 512 * 2);
    unsigned short* qc_b  = (unsigned short*)alloc((size_t)Mq * 256 * 2);
    unsigned short* qk_b  = (unsigned short*)alloc((size_t)Mq * 256 * 2);
    float*          cross = (float*)alloc((size_t)Mq * 256 * 4);

    unsigned short* x_b = (unsigned short*)cross;
    float* off_att = (float*)qkb;
    float* gbuf = (float*)mem_b;
    float* x2   = (float*)((char*)mem_b + (size_t)Mq * 512 * 4);
    unsigned short* z_b = (unsigned short*)((char*)x2 + (size_t)Mq * 256 * 4);
    unsigned short* hidden_b = (unsigned short*)((char*)z_b + (size_t)Mq * 256 * 2);

    float* out0    = (float*)d_out;
    float* aw_out  = out0 + (size_t)Mq * 256;
    float* loc_out = aw_out + (size_t)Mq * 128;

    dim3 blk(256);
    const int tMq = (Mq + 63) / 64;    // 113
    const int tv  = (Mv + 63) / 64;    // 1662

    // 1. prep
    TPack tp;
    tp.d[0]  = { Wq,             WtQK,             256, 256,    0 };
    tp.d[1]  = { Wk,             WtQK + 256 * 256, 256, 256,   64 };
    tp.d[2]  = { Wv,             WtV,              256, 256,  128 };
    tp.d[3]  = { Wo,             WtO,              256, 256,  192 };
    tp.d[4]  = { Wvd,            WtVD,             256, 256,  256 };
    tp.d[5]  = { Woff,           WtOA,             256, 256,  320 };
    tp.d[6]  = { Watt,           WtOA + 256 * 256, 256, 128,  384 };
    tp.d[7]  = { Wop,            WtOP,             256, 256,  416 };
    tp.d[8]  = { Wg,             WtGF,             512, 512,  480 };  // 128 tiles: Wg1^T
    tp.d[9]  = { Wg + 256 * 512, Wg2T,             256, 512,  608 };  // 128 tiles: Wg2^T
    tp.d[10] = { W1,             Wt1,              256, 1024, 736 };
    tp.d[11] = { W2,             Wt2,             1024, 256,  992 };
    tp.bq = bq; tp.bk = bk; tp.boff = boff; tp.batt = batt;
    tp.bqk = bqk; tp.boa = boa;
    tp.Wop_src = Wop; tp.Wg_src = Wg; tp.bop_src = bop; tp.bg_src = bg;
    tp.WopRow = WopRow; tp.bgg = bgg;
    prep_kernel<<<10534, blk, 0, stream>>>(
        tp, queries, query_pos, ln1_s, ln1_b, x_b, qk_b, memory, mem_b, memN);

    // 2. batched {QK, V, WopG} — persistent BN=128
    {
        GB g; g.nd = 3;
        g.d[0] = { qk_b, WtQK, bqk, nullptr, nullptr, qkb,
                   nullptr, nullptr, nullptr, nullptr,
                   Mq, 256, 512, 4, 0, 512, 0, 0, 0 };
        g.d[1] = { x_b, WtV, bv, nullptr, nullptr, vb_buf,
                   nullptr, nullptr, nullptr, nullptr,
                   Mq, 256, 256, 2, tMq * 4, 256, 0, 0, 0 };
        g.d[2] = { Wg2T, WopRow, nullptr, nullptr, nullptr, WtGF,
                   nullptr, nullptr, nullptr, nullptr,
                   512, 256, 256, 2, tMq * 6, 512, 256, 0, 0 };
        g.tot = tMq * 6 + 16;   // 694
        gemm_pipe<128><<<g.tot, blk, 0, stream>>>(g);
    }

    // 3. co-resident {self-attention ∥ val GEMM}
    attn_val<<<960 + VGRID, blk, 0, stream>>>(
        qkb, vb_buf, av_buf, mem_b, WtVD, bvd, val_b, Mv, tv * 2);

    // 4. x1 = attnV @ Wo + bo + queries; fused ln2(+pos) -> qc_b  (BN=256)
    {
        GB g; g.nd = 1;
        g.d[0] = { av_buf, WtO, bo, queries, x1, xs_cat,
                   ln2_s, ln2_b, query_pos, qc_b,
                   Mq, 256, 256, 1, 0, 512, 0, 0, 0 };
        g.tot = tMq;
        gemm_pipe<256><<<tMq, blk, 0, stream>>>(g);
    }

    // 5. off|att logits
    {
        GB g; g.nd = 1;
        g.d[0] = { qc_b, WtOA, boa, nullptr, off_att, nullptr,
                   nullptr, nullptr, nullptr, nullptr,
                   Mq, 256, 384, 3, 0, 384, 0, 0, 0 };
        g.tot = tMq * 3;
        gemm_pipe<128><<<g.tot, blk, 0, stream>>>(g);
    }

    // 6. softmax + loc + bilinear sampling -> xs_cat[:,256:]
    sample_fused<<<Mq, blk, 0, stream>>>(off_att, refp, val_b, shapes, starts,
                                         aw_out, loc_out, xs_cat, NV);

    // 7. batched { cross, g=sigmoid([x1|samp]@WtGF+bgg) }
    {
        GB g; g.nd = 2;
        g.d[0] = { xs_cat + 256, WtOP, bop, nullptr, cross, nullptr,
                   nullptr, nullptr, nullptr, nullptr,
                   Mq, 256, 256, 2, 0, 0, 0, 0, 512 };
        g.d[1] = { xs_cat, WtGF, bgg, nullptr, gbuf, nullptr,
                   nullptr, nullptr, nullptr, nullptr,
                   Mq, 512, 512, 4, tMq * 2, 0, 0, 2, 0 };
        g.tot = tMq * 6;
        gemm_pipe<128><<<g.tot, blk, 0, stream>>>(g);
    }

    // 8. x2 + ln3
    gate_ln3<<<Mq, blk, 0, stream>>>(gbuf, x1, cross, ln3_s, ln3_b, x2, z_b);

    // 9. hidden = relu(z @ W1 + b1)
    {
        GB g; g.nd = 1;
        g.d[0] = { z_b, Wt1, b1, nullptr, nullptr, hidden_b,
                   nullptr, nullptr, nullptr, nullptr,
                   Mq, 256, 1024, 8, 0, 1024, 0, 1, 0 };
        g.tot = tMq * 8;
        gemm_pipe<128><<<g.tot, blk, 0, stream>>>(g);
    }

    // 10. out0 = hidden @ W2 + b2 + x2
    {
        GB g; g.nd = 1;
        g.d[0] = { hidden_b, Wt2, b2, x2, out0, nullptr,
                   nullptr, nullptr, nullptr, nullptr,
                   Mq, 1024, 256, 2, 0, 256, 0, 0, 0 };
        g.tot = tMq * 2;
        gemm_pipe<128><<<g.tot, blk, 0, stream>>>(g);
    }
}